// Round 12
// baseline (503.134 us; speedup 1.0000x reference)
//
#include <hip/hip_runtime.h>
#include <math.h>

#define NB 256
#define SEQ 65536
#define NP 2047
#define NPM 2046
#define LEN1 2047
#define LEN2 1023
#define LEN3 511
#define LEN2P 1024   // h1 row stride (16B-aligned float4 rows)
#define LEN3P 512    // h2 row stride
#define C1 32
#define C2 64
#define C3 128
#define NPART 2048

// workspace offsets (floats). Region timeline:
//   Y2: gemm Wt -> h1 (pool1 out, stride 1024) -> h2 (pool2t out, stride 512)
//   Y1: y1 (conv1 out) -> pmaxT (conv2 out) -> y3t (conv3 out)
#define OFF_X3   0
#define SZ_X3    (NB*3*NP)
#define OFF_DMAX (OFF_X3 + SZ_X3)
#define SZ_DMAX  (NB*NPM)
#define OFF_Y1   (OFF_DMAX + SZ_DMAX)
#define SZ_Y1    (NB*C1*LEN1)
#define OFF_Y2   (OFF_Y1 + SZ_Y1)
#define SZ_Y2    (NB*C2*LEN2)
#define OFF_S1   (OFF_Y2 + SZ_Y2)
#define OFF_S2   (OFF_S1 + 2*C1)
#define OFF_S3   (OFF_S2 + 2*C2)
#define OFF_W2C  (OFF_S3 + 2*C3)
#define OFF_W3C  (OFF_W2C + C1*C2*3)
#define OFF_PS   (OFF_W3C + C2*C3*3)
#define OFF_PQ   (OFF_PS + C3*NPART)
#define OFF_WT   OFF_Y2   // gemm W^T (dead after gemm)
#define OFF_H1   OFF_Y2   // pooled bn1 activations [b][i][m], stride LEN2P (8.39M < 16.76M)
#define OFF_PMAX OFF_Y1   // conv2 pooled-raw out [b][m][c], m<LEN3
#define OFF_H2   OFF_Y2   // pooled bn2 activations [b][i][m], stride LEN3P (8.39M)
#define OFF_Y3T  OFF_Y1   // y3 transposed [b][l][c]

#define ACCS16(X) X(0) X(1) X(2) X(3) X(4) X(5) X(6) X(7) \
                  X(8) X(9) X(10) X(11) X(12) X(13) X(14) X(15)
#define ACCS32(X) ACCS16(X) X(16) X(17) X(18) X(19) X(20) X(21) X(22) X(23) \
                  X(24) X(25) X(26) X(27) X(28) X(29) X(30) X(31)
#define POOL16(X) X(0,0,1) X(1,2,3) X(2,4,5) X(3,6,7) X(4,8,9) X(5,10,11) X(6,12,13) X(7,14,15) \
                  X(8,16,17) X(9,18,19) X(10,20,21) X(11,22,23) X(12,24,25) X(13,26,27) X(14,28,29) X(15,30,31)

#define RED6(v) v += __shfl_xor(v,32,64); v += __shfl_xor(v,16,64); \
                v += __shfl_xor(v, 8,64); v += __shfl_xor(v, 4,64); \
                v += __shfl_xor(v, 2,64); v += __shfl_xor(v, 1,64);

// conv K-loop: 34 wave-uniform h scalars via broadcast GLOBAL loads (vmcnt domain —
// in-order, fine-grained waits, compiler can pipeline across iterations; lgkm
// (SMEM/LDS) proved un-pipelineable in R8/R10/R11). hrow is 16B-aligned.
#define HQG float hh0 = hrow[-1]; \
  float4 q0 = *(const float4*)(hrow+0),  q1 = *(const float4*)(hrow+4), \
         q2 = *(const float4*)(hrow+8),  q3 = *(const float4*)(hrow+12), \
         q4 = *(const float4*)(hrow+16), q5 = *(const float4*)(hrow+20), \
         q6 = *(const float4*)(hrow+24), q7 = *(const float4*)(hrow+28); \
  float hh33 = hrow[32]; \
  float hh1=q0.x,hh2=q0.y,hh3=q0.z,hh4=q0.w,hh5=q1.x,hh6=q1.y,hh7=q1.z,hh8=q1.w, \
        hh9=q2.x,hh10=q2.y,hh11=q2.z,hh12=q2.w,hh13=q3.x,hh14=q3.y,hh15=q3.z,hh16=q3.w, \
        hh17=q4.x,hh18=q4.y,hh19=q4.z,hh20=q4.w,hh21=q5.x,hh22=q5.y,hh23=q5.z,hh24=q5.w, \
        hh25=q6.x,hh26=q6.y,hh27=q6.z,hh28=q6.w,hh29=q7.x,hh30=q7.y,hh31=q7.z,hh32=q7.w;
#define CF(p,j0,j1,j2) acc##p = fmaf(w0_, hh##j0, acc##p); \
                       acc##p = fmaf(w1_, hh##j1, acc##p); \
                       acc##p = fmaf(w2_, hh##j2, acc##p);
#define CFALL CF(0,0,1,2)    CF(1,1,2,3)    CF(2,2,3,4)    CF(3,3,4,5) \
              CF(4,4,5,6)    CF(5,5,6,7)    CF(6,6,7,8)    CF(7,7,8,9) \
              CF(8,8,9,10)   CF(9,9,10,11)  CF(10,10,11,12) CF(11,11,12,13) \
              CF(12,12,13,14) CF(13,13,14,15) CF(14,14,15,16) CF(15,15,16,17) \
              CF(16,16,17,18) CF(17,17,18,19) CF(18,18,19,20) CF(19,19,20,21) \
              CF(20,20,21,22) CF(21,21,22,23) CF(22,22,23,24) CF(23,23,24,25) \
              CF(24,24,25,26) CF(25,25,26,27) CF(26,26,27,28) CF(27,27,28,29) \
              CF(28,28,29,30) CF(29,29,30,31) CF(30,30,31,32) CF(31,31,32,33)

// ---------------- K1: patch mean/std + dmax (transposed) + x3-ch2 bias init ----------------
__global__ __launch_bounds__(256) void k_patch(const float* __restrict__ x, const float* __restrict__ c1b,
                                               float* __restrict__ ws){
  float* x3    = ws + OFF_X3;
  float* dmaxT = ws + OFF_DMAX;        // [NPM][NB]
  int b = blockIdx.y;
  int chunk = blockIdx.x;              // 0..31, 2048 floats each
  const float* xr = x + (size_t)b*SEQ + chunk*2048;
  __shared__ float Ss[65], Qs[65], Dm[65];
  int w = threadIdx.x >> 6;
  int l = threadIdx.x & 63;
  #pragma unroll
  for (int i=0;i<2;i++){
    int seg = w*2 + i;
    int off = seg*256;
    float4 A = *(const float4*)(xr + off + l*4);
    float4 Bh = make_float4(0.f,0.f,0.f,0.f);
    if (l >= 56){
      int g = chunk*2048 + off + 256 + (l-56)*4;
      if (g + 3 < SEQ) Bh = *(const float4*)(xr + off + 256 + (l-56)*4);
    }
    int src = (l+8) & 63;
    float p0 = __shfl(A.x, src, 64), p1 = __shfl(A.y, src, 64),
          p2 = __shfl(A.z, src, 64), p3 = __shfl(A.w, src, 64);
    if (l >= 56){ p0=Bh.x; p1=Bh.y; p2=Bh.z; p3=Bh.w; }
    float s = (A.x+A.y)+(A.z+A.w);
    float q = fmaf(A.x,A.x, fmaf(A.y,A.y, fmaf(A.z,A.z, A.w*A.w)));
    float d = fmaxf(fmaxf(p0-A.x, p1-A.y), fmaxf(p2-A.z, p3-A.w));
    #pragma unroll
    for (int o=1;o<8;o<<=1){
      s += __shfl_xor(s,o,64);
      q += __shfl_xor(q,o,64);
      d  = fmaxf(d, __shfl_xor(d,o,64));
    }
    if ((l&7)==0){ int m = seg*8 + (l>>3); Ss[m]=s; Qs[m]=q; Dm[m]=d; }
  }
  if (w==0){
    float s=0.f,q=0.f,d=-1e30f;
    if (l < 8){
      int g = chunk*2048 + 2048 + l*4;
      if (g+3 < SEQ){
        float4 A = *(const float4*)(xr + 2048 + l*4);
        float4 P = make_float4(0.f,0.f,0.f,0.f);
        if (g+35 < SEQ) P = *(const float4*)(xr + 2048 + 32 + l*4);
        s = (A.x+A.y)+(A.z+A.w);
        q = fmaf(A.x,A.x, fmaf(A.y,A.y, fmaf(A.z,A.z, A.w*A.w)));
        d = fmaxf(fmaxf(P.x-A.x, P.y-A.y), fmaxf(P.z-A.z, P.w-A.w));
      }
    }
    #pragma unroll
    for (int o=1;o<8;o<<=1){
      s += __shfl_xor(s,o,64);
      q += __shfl_xor(q,o,64);
      d  = fmaxf(d, __shfl_xor(d,o,64));
    }
    if (l==0){ Ss[64]=s; Qs[64]=q; Dm[64]=d; }
  }
  __syncthreads();
  if (threadIdx.x < 64){
    int j = threadIdx.x;
    int p = chunk*64 + j;
    if (p < NP){
      float S = Ss[j]+Ss[j+1];
      float Q = Qs[j]+Qs[j+1];
      float mean = S*(1.0f/64.0f);
      float var  = (Q - S*mean)*(1.0f/63.0f);   // ddof=1
      x3[(b*3+0)*NP + p] = mean;
      x3[(b*3+1)*NP + p] = sqrtf(fmaxf(var,0.0f));
      x3[(b*3+2)*NP + p] = c1b[p];              // bias init (gemm atomically adds on top)
      if (p < NPM) dmaxT[(size_t)p*NB + b] = fmaxf(Dm[j], Dm[j+1]);
    }
  }
}

// ---------------- K_trW: conv1_w [NP][NPM] -> Wt [NPM][NP] ----------------
__global__ __launch_bounds__(256) void k_trW(const float* __restrict__ W, float* __restrict__ ws){
  float* Wt = ws + OFF_WT;
  __shared__ float t[64][65];
  int ko = blockIdx.x*64;
  int oo = blockIdx.y*64;
  int tx = threadIdx.x & 63, tw = threadIdx.x >> 6;
  #pragma unroll
  for (int r=0;r<16;r++){
    int rr = tw*16 + r;
    int o = oo + rr, k = ko + tx;
    t[rr][tx] = (o < NP && k < NPM) ? W[(size_t)o*NPM + k] : 0.f;
  }
  __syncthreads();
  #pragma unroll
  for (int r=0;r<16;r++){
    int rr = tw*16 + r;
    int k = ko + rr, o = oo + tx;
    if (k < NPM && o < NP) Wt[(size_t)k*NP + o] = t[tx][rr];
  }
}

// ---------------- K_wt: pack conv weights to [(i*3+tap)][c] ----------------
__global__ __launch_bounds__(256) void k_wt(const float* __restrict__ w2, const float* __restrict__ w3, float* __restrict__ ws){
  float* w2c = ws + OFF_W2C;
  float* w3c = ws + OFF_W3C;
  int t = blockIdx.x*256 + threadIdx.x;
  if (t < C1*3*C2){
    int r = t / C2, c = t - r*C2;          // r = i*3+tap
    int i = r/3, tap = r - i*3;
    w2c[t] = w2[(c*C1+i)*3 + tap];
  }
  if (t < C2*3*C3){
    int r = t / C3, c = t - r*C3;          // r = i*3+tap
    int i = r/3, tap = r - i*3;
    w3c[t] = w3[(c*C2+i)*3 + tap];
  }
}

// ---------------- K2: d2[b,o] += sum_k At[k,b]*Wt[k,o]  (no LDS, no barriers) ----------------
__global__ __launch_bounds__(256) void k_gemm(float* __restrict__ ws){
  const float* At = ws + OFF_DMAX;   // [NPM][NB]
  const float* Wt = ws + OFF_WT;     // [NPM][NP]
  float* x3 = ws + OFF_X3;
  int o  = blockIdx.x*64 + (threadIdx.x & 63);
  int w  = __builtin_amdgcn_readfirstlane(threadIdx.x >> 6);
  int bg = blockIdx.y*128 + w*32;
  int ks = blockIdx.z*256;
  int ke = min(ks+256, NPM);
  int oL = min(o, NP-1);
#define DG(c) float acc##c = 0.f;
  ACCS32(DG)
  const float* wp = Wt + oL;
  #pragma unroll 2
  for (int k=ks; k<ke; ++k){
    float wv = wp[(size_t)k*NP];
    const float* ar = At + (size_t)k*NB + bg;
#define FG(c) acc##c = fmaf(ar[c], wv, acc##c);
    ACCS32(FG)
  }
  if (o < NP){
    float* xp = x3 + 2*NP + o;
#define SG(c) atomicAdd(xp + (size_t)(bg+c)*3*NP, acc##c);
    ACCS32(SG)
  }
}

// ---------------- K3: conv1 (3->32, k=5, pad=2), plain ----------------
__global__ __launch_bounds__(256) void k_conv1(const float* __restrict__ w1, const float* __restrict__ b1, float* __restrict__ ws){
  const float* x3 = ws + OFF_X3;
  float* y1 = ws + OFF_Y1;
  int b = blockIdx.y;
  int l = blockIdx.x*256 + threadIdx.x;
  bool valid = (l < LEN1);
  float xin[3][5];
  #pragma unroll
  for (int i=0;i<3;i++){
    #pragma unroll
    for (int j=0;j<5;j++){
      int t = l + j - 2;
      xin[i][j] = (valid && t >= 0 && t < LEN1) ? x3[(b*3+i)*NP + t] : 0.f;
    }
  }
  #pragma unroll 8
  for (int c=0;c<C1;c++){
    float a = b1[c];
    #pragma unroll
    for (int i=0;i<3;i++){
      #pragma unroll
      for (int j=0;j<5;j++) a = fmaf(w1[(c*3+i)*5+j], xin[i][j], a);
    }
    if (valid) y1[(b*C1+c)*LEN1 + l] = a;
  }
}

// ---------------- stats (layer1): per-(b,c) sum/sumsq over y1 ----------------
__global__ __launch_bounds__(256) void k_stats(const float* __restrict__ y, float* __restrict__ ps,
                                               float* __restrict__ pq, int C, int L, int npart){
  int b = blockIdx.x, c = blockIdx.y;
  const float* p = y + ((size_t)b*C + c)*L;
  float s=0.f, q=0.f;
  for (int i=threadIdx.x; i<L; i+=256){ float v=p[i]; s+=v; q=fmaf(v,v,q); }
  __shared__ float rs[4], rq[4];
  RED6(s) RED6(q)
  int wid = threadIdx.x>>6, lane = threadIdx.x&63;
  if (lane==0){ rs[wid]=s; rq[wid]=q; }
  __syncthreads();
  if (threadIdx.x==0){
    ps[c*npart + b] = rs[0]+rs[1]+rs[2]+rs[3];
    pq[c*npart + b] = rq[0]+rq[1]+rq[2]+rq[3];
  }
}

// ---------------- finalize BN from partials ----------------
__global__ __launch_bounds__(256) void k_fin(const float* __restrict__ ps, const float* __restrict__ pq,
                                             const float* __restrict__ g, const float* __restrict__ be,
                                             float* __restrict__ stats, int C, int npart, double invN){
  int c = blockIdx.x;
  double s=0.0, q=0.0;
  for (int j=threadIdx.x; j<npart; j+=256){ s += (double)ps[c*npart+j]; q += (double)pq[c*npart+j]; }
  #pragma unroll
  for (int off=32; off; off>>=1){ s += __shfl_xor(s,off,64); q += __shfl_xor(q,off,64); }
  __shared__ double rs[4], rq[4];
  int wid = threadIdx.x>>6, lane=threadIdx.x&63;
  if (lane==0){ rs[wid]=s; rq[wid]=q; }
  __syncthreads();
  if (threadIdx.x==0){
    double S = rs[0]+rs[1]+rs[2]+rs[3];
    double Q = rq[0]+rq[1]+rq[2]+rq[3];
    double mean = S*invN;
    double var  = Q*invN - mean*mean;
    double a = (double)g[c] / sqrt(var + 1e-5);
    stats[c]   = (float)a;
    stats[C+c] = (float)((double)be[c] - mean*a);
  }
}

// ---------------- K4: pool1 — h1[b][i][m] = relu(bn1(max(y1[2m], y1[2m+1]))), stride LEN2P ----------------
__global__ __launch_bounds__(256) void k_pool1(float* __restrict__ ws){
  const float* y1 = ws + OFF_Y1;
  const float* st = ws + OFF_S1;
  float* h1 = ws + OFF_H1;
  int b = blockIdx.z, i = blockIdx.y;
  int m = blockIdx.x*256 + threadIdx.x;
  if (m < LEN2){
    float sa = st[i], sb = st[C1+i];
    const float* yr = y1 + ((size_t)b*C1 + i)*LEN1 + 2*m;
    float v = fmaxf(yr[0], yr[1]);
    h1[((size_t)b*C1 + i)*LEN2P + m] = fmaxf(fmaf(sa, v, sb), 0.f);
  }
}

// ---------------- K5: conv2 (32->64) — lanes=channel; h via broadcast VMEM; weights via VMEM ----------------
// 4 waves = 4 pos-groups of 32; all hot-loop operands in vmcnt domain (pipelineable).
// In-thread maxpool pairs -> writes pooled-raw pmaxT[b][m][c] + per-channel stats (no shuffles).
__global__ __launch_bounds__(256) void k_conv2(const float* __restrict__ b2, float* __restrict__ ws){
  const float* h1  = ws + OFF_H1;     // [b][i][m], stride LEN2P, 16B-aligned rows
  const float* w2c = ws + OFF_W2C;    // [(i*3+tap)][c]
  float* pmaxT = ws + OFF_PMAX;       // [b][m][c], m<LEN3
  float* ps = ws + OFF_PS;
  float* pq = ws + OFF_PQ;
  int b = blockIdx.y;
  int blk = blockIdx.x;               // 0..7 (128 positions each)
  int w  = __builtin_amdgcn_readfirstlane(threadIdx.x >> 6);
  int lane = threadIdx.x & 63;
  int p0 = blk*128 + w*32;            // wave-uniform
  int c  = lane;
#define AD2(p) float acc##p = b2[c];
  ACCS32(AD2)
  const float* hb = h1 + (size_t)b*C1*LEN2P + p0;
  const float* wb = w2c + c;
  #pragma unroll 2
  for (int i=0;i<C1;i++){
    const float* hrow = hb + (size_t)i*LEN2P;   // broadcast VMEM, 16B-aligned
    HQG
    if (p0 == 0) hh0 = 0.f;
    if (p0 == 992){ hh32 = 0.f; hh33 = 0.f; }   // positions 1023,1024 invalid
    const float* wv = wb + (i*3)*C2;            // per-lane coalesced VMEM
    float w0_ = wv[0], w1_ = wv[C2], w2_ = wv[2*C2];
    CFALL
  }
  int m0 = p0 >> 1;
  float* pp = pmaxT + ((size_t)b*LEN3 + m0)*C2 + c;
#define PST2(j,e,o) if (m0 + j < LEN3) pp[(size_t)(j)*C2] = fmaxf(acc##e, acc##o);
  POOL16(PST2)
  float ss = 0.f, qq = 0.f;
#define SAC2(p) if (p0 + p < LEN2){ ss += acc##p; qq = fmaf(acc##p, acc##p, qq); }
  ACCS32(SAC2)
  __shared__ float es[4][64], eq[4][64];
  es[w][lane] = ss; eq[w][lane] = qq;
  __syncthreads();
  if (w == 0){
    int pidx = b*8 + blk;
    float S = es[0][lane]+es[1][lane]+es[2][lane]+es[3][lane];
    float Q = eq[0][lane]+eq[1][lane]+eq[2][lane]+eq[3][lane];
    ps[lane*NPART + pidx] = S;
    pq[lane*NPART + pidx] = Q;
  }
}

// ---------------- K6: pool2t — h2[b][c][m] = relu(bn2(pmaxT[b][m][c])), stride LEN3P ----------------
__global__ __launch_bounds__(256) void k_pool2t(float* __restrict__ ws){
  const float* pm = ws + OFF_PMAX;   // [b][m][c]
  const float* st = ws + OFF_S2;
  float* h2 = ws + OFF_H2;           // [b][c][m]
  int b = blockIdx.y;
  int m0 = blockIdx.x*128;
  __shared__ float T[128][65];
  int c = threadIdx.x & 63;
  int r = threadIdx.x >> 6;          // 0..3
  float sa = st[c], sb = st[C2+c];
  for (int mm = r; mm < 128; mm += 4){
    int m = m0 + mm;
    float v = 0.f;
    if (m < LEN3) v = fmaxf(fmaf(sa, pm[((size_t)b*LEN3 + m)*C2 + c], sb), 0.f);
    T[mm][c] = v;
  }
  __syncthreads();
  int half = threadIdx.x >> 7;       // 0/1
  int mm = threadIdx.x & 127;
  int m = m0 + mm;
  if (m < LEN3){
    for (int cc = 0; cc < 32; cc++){
      int ch = cc*2 + half;
      h2[((size_t)b*C2 + ch)*LEN3P + m] = T[mm][ch];
    }
  }
}

// ---------------- K7: conv3 (64->128) — lanes=channel; h via broadcast VMEM; weights via VMEM ----------------
// 4 waves: zh = w&1 (64-ch half), pg = w>>1 (32-pos group); all hot-loop operands in vmcnt.
__global__ __launch_bounds__(256) void k_conv3(const float* __restrict__ b3, float* __restrict__ ws){
  const float* h2  = ws + OFF_H2;     // [b][i][m], stride LEN3P, 16B-aligned rows
  const float* w3c = ws + OFF_W3C;    // [(i*3+tap)][c]
  float* y3t = ws + OFF_Y3T;          // [b][l][c]
  float* ps = ws + OFF_PS;
  float* pq = ws + OFF_PQ;
  int b = blockIdx.y;
  int blk = blockIdx.x;               // 0..7 (64 positions each)
  int w  = __builtin_amdgcn_readfirstlane(threadIdx.x >> 6);
  int lane = threadIdx.x & 63;
  int zh = w & 1, pg = w >> 1;
  int p0 = blk*64 + pg*32;            // wave-uniform
  int c  = zh*64 + lane;
#define AD3(p) float acc##p = b3[c];
  ACCS32(AD3)
  const float* hb = h2 + (size_t)b*C2*LEN3P + p0;
  const float* wb = w3c + c;
  #pragma unroll 2
  for (int i=0;i<C2;i++){
    const float* hrow = hb + (size_t)i*LEN3P;   // broadcast VMEM, 16B-aligned
    HQG
    if (p0 == 0) hh0 = 0.f;
    if (p0 == 480){ hh32 = 0.f; hh33 = 0.f; }   // positions 511,512 invalid
    const float* wv = wb + (i*3)*C3;            // per-lane coalesced VMEM
    float w0_ = wv[0], w1_ = wv[C3], w2_ = wv[2*C3];
    CFALL
  }
  float* yp = y3t + ((size_t)b*LEN3 + p0)*C3 + c;
#define STC(p) if (p0 + p < LEN3) yp[(size_t)(p)*C3] = acc##p;
  ACCS32(STC)
  float ss = 0.f, qq = 0.f;
#define SAC(p) if (p0 + p < LEN3){ ss += acc##p; qq = fmaf(acc##p, acc##p, qq); }
  ACCS32(SAC)
  __shared__ float es[4][64], eq[4][64];
  es[w][lane] = ss; eq[w][lane] = qq;
  __syncthreads();
  if (w < 2){
    int cc = (w & 1)*64 + lane;
    int pidx = b*8 + blk;
    ps[cc*NPART + pidx] = es[w][lane] + es[w+2][lane];
    pq[cc*NPART + pidx] = eq[w][lane] + eq[w+2][lane];
  }
}

// ---------------- K9: bn3+relu+mean over y3t [b][l][c] ----------------
__global__ __launch_bounds__(1024) void k_out(float* __restrict__ out, const float* __restrict__ ws){
  const float* y3t = ws + OFF_Y3T;
  const float* st = ws + OFF_S3;
  int b = blockIdx.x;
  int tid = threadIdx.x;
  int c = tid & 127, ph = tid >> 7;     // 8 phases
  float a = st[c], sh = st[C3+c];
  const float* yb = y3t + (size_t)b*LEN3*C3 + c;
  float s = 0.f;
  for (int l=ph; l<LEN3; l+=8) s += fmaxf(fmaf(a, yb[(size_t)l*C3], sh), 0.f);
  __shared__ float red[1024];
  red[tid] = s;
  __syncthreads();
  if (tid < 128){
    float t = 0.f;
    #pragma unroll
    for (int k=0;k<8;k++) t += red[k*128 + tid];
    out[b*C3 + tid] = t * (1.0f/511.0f);
  }
}

extern "C" void kernel_launch(void* const* d_in, const int* in_sizes, int n_in,
                              void* d_out, int out_size, void* d_ws, size_t ws_size,
                              hipStream_t stream) {
  const float* x   = (const float*)d_in[0];
  const float* c1w = (const float*)d_in[1];
  const float* c1b = (const float*)d_in[2];
  const float* w1  = (const float*)d_in[3];
  const float* b1  = (const float*)d_in[4];
  const float* g1  = (const float*)d_in[5];
  const float* be1 = (const float*)d_in[6];
  const float* w2  = (const float*)d_in[7];
  const float* b2  = (const float*)d_in[8];
  const float* g2  = (const float*)d_in[9];
  const float* be2 = (const float*)d_in[10];
  const float* w3  = (const float*)d_in[11];
  const float* b3  = (const float*)d_in[12];
  const float* g3  = (const float*)d_in[13];
  const float* be3 = (const float*)d_in[14];
  float* ws  = (float*)d_ws;
  float* out = (float*)d_out;

  hipLaunchKernelGGL(k_patch,  dim3(32,NB), dim3(256), 0, stream, x, c1b, ws);
  hipLaunchKernelGGL(k_trW,    dim3(32,32), dim3(256), 0, stream, c1w, ws);
  hipLaunchKernelGGL(k_wt,     dim3((C2*3*C3+255)/256), dim3(256), 0, stream, w2, w3, ws);
  hipLaunchKernelGGL(k_gemm,   dim3(32,2,8), dim3(256), 0, stream, ws);
  hipLaunchKernelGGL(k_conv1,  dim3(8,NB), dim3(256), 0, stream, w1, b1, ws);
  hipLaunchKernelGGL(k_stats,  dim3(NB,C1), dim3(256), 0, stream, ws+OFF_Y1, ws+OFF_PS, ws+OFF_PQ, C1, LEN1, NB);
  hipLaunchKernelGGL(k_fin,    dim3(C1), dim3(256), 0, stream, ws+OFF_PS, ws+OFF_PQ, g1, be1, ws+OFF_S1, C1, NB, 1.0/((double)NB*LEN1));
  hipLaunchKernelGGL(k_pool1,  dim3(4,C1,NB), dim3(256), 0, stream, ws);
  hipLaunchKernelGGL(k_conv2,  dim3(8,NB), dim3(256), 0, stream, b2, ws);
  hipLaunchKernelGGL(k_fin,    dim3(C2), dim3(256), 0, stream, ws+OFF_PS, ws+OFF_PQ, g2, be2, ws+OFF_S2, C2, NPART, 1.0/((double)NB*LEN2));
  hipLaunchKernelGGL(k_pool2t, dim3(4,NB), dim3(256), 0, stream, ws);
  hipLaunchKernelGGL(k_conv3,  dim3(8,NB), dim3(256), 0, stream, b3, ws);
  hipLaunchKernelGGL(k_fin,    dim3(C3), dim3(256), 0, stream, ws+OFF_PS, ws+OFF_PQ, g3, be3, ws+OFF_S3, C3, NPART, 1.0/((double)NB*LEN3));
  hipLaunchKernelGGL(k_out,    dim3(NB), dim3(1024), 0, stream, out, ws);
}

// Round 13
// 460.123 us; speedup vs baseline: 1.0935x; 1.0935x over previous
//
#include <hip/hip_runtime.h>
#include <math.h>

#define NB 256
#define SEQ 65536
#define NP 2047
#define NPM 2046
#define LEN1 2047
#define LEN2 1023
#define LEN3 511
#define C1 32
#define C2 64
#define C3 128
#define NPART 2048

// workspace offsets (floats). Region timeline:
//   Y2: gemm Wt -> h1 (pool1 out) -> h2 (pool2t out)
//   Y1: y1 (conv1 out) -> pmaxT (conv2 out) -> y3t (conv3 out)
#define OFF_X3   0
#define SZ_X3    (NB*3*NP)
#define OFF_DMAX (OFF_X3 + SZ_X3)
#define SZ_DMAX  (NB*NPM)
#define OFF_Y1   (OFF_DMAX + SZ_DMAX)
#define SZ_Y1    (NB*C1*LEN1)
#define OFF_Y2   (OFF_Y1 + SZ_Y1)
#define SZ_Y2    (NB*C2*LEN2)
#define OFF_S1   (OFF_Y2 + SZ_Y2)
#define OFF_S2   (OFF_S1 + 2*C1)
#define OFF_S3   (OFF_S2 + 2*C2)
#define OFF_W2C  (OFF_S3 + 2*C3)
#define OFF_W3C  (OFF_W2C + C1*C2*3)
#define OFF_PS   (OFF_W3C + C2*C3*3)
#define OFF_PQ   (OFF_PS + C3*NPART)
#define OFF_WT   OFF_Y2   // gemm W^T (dead after gemm)
#define OFF_H1   OFF_Y2   // pooled bn1 activations [b][i][m], m<LEN2
#define OFF_PMAX OFF_Y1   // conv2 pooled-raw out [b][m][c], m<LEN3
#define OFF_H2   OFF_Y2   // pooled bn2 activations [b][i][m], m<LEN3
#define OFF_Y3T  OFF_Y1   // y3 transposed [b][l][c]

#define ACCS16(X) X(0) X(1) X(2) X(3) X(4) X(5) X(6) X(7) \
                  X(8) X(9) X(10) X(11) X(12) X(13) X(14) X(15)
#define ACCS32(X) ACCS16(X) X(16) X(17) X(18) X(19) X(20) X(21) X(22) X(23) \
                  X(24) X(25) X(26) X(27) X(28) X(29) X(30) X(31)
#define HS34(X) X(0) X(1) X(2) X(3) X(4) X(5) X(6) X(7) X(8) X(9) X(10) X(11) \
                X(12) X(13) X(14) X(15) X(16) X(17) X(18) X(19) X(20) X(21) \
                X(22) X(23) X(24) X(25) X(26) X(27) X(28) X(29) X(30) X(31) X(32) X(33)
#define POOL16(X) X(0,0,1) X(1,2,3) X(2,4,5) X(3,6,7) X(4,8,9) X(5,10,11) X(6,12,13) X(7,14,15) \
                  X(8,16,17) X(9,18,19) X(10,20,21) X(11,22,23) X(12,24,25) X(13,26,27) X(14,28,29) X(15,30,31)

#define RED6(v) v += __shfl_xor(v,32,64); v += __shfl_xor(v,16,64); \
                v += __shfl_xor(v, 8,64); v += __shfl_xor(v, 4,64); \
                v += __shfl_xor(v, 2,64); v += __shfl_xor(v, 1,64);

// conv K-loop, unrolled x2: both iterations' 34 wave-uniform h scalars (SMEM s_load)
// are loaded as named scalars BEFORE either FMA block — SMEM is out-of-order so each
// lgkm drain is all-or-nothing; grouping 2 iterations halves the drain count
// (R9 ceiling was 58% = 192 FMA cyc / (192 + ~140 drain) per iteration).
#define HLA(j) float hh##j = hpA[j];
#define HLB(j) float gg##j = hpB[j];
#define CFA(p,j0,j1,j2) acc##p = fmaf(w0a_, hh##j0, acc##p); \
                        acc##p = fmaf(w1a_, hh##j1, acc##p); \
                        acc##p = fmaf(w2a_, hh##j2, acc##p);
#define CFB(p,j0,j1,j2) acc##p = fmaf(w0b_, gg##j0, acc##p); \
                        acc##p = fmaf(w1b_, gg##j1, acc##p); \
                        acc##p = fmaf(w2b_, gg##j2, acc##p);
#define CONVSTEPS(CF_) CF_(0,0,1,2)    CF_(1,1,2,3)    CF_(2,2,3,4)    CF_(3,3,4,5) \
              CF_(4,4,5,6)    CF_(5,5,6,7)    CF_(6,6,7,8)    CF_(7,7,8,9) \
              CF_(8,8,9,10)   CF_(9,9,10,11)  CF_(10,10,11,12) CF_(11,11,12,13) \
              CF_(12,12,13,14) CF_(13,13,14,15) CF_(14,14,15,16) CF_(15,15,16,17) \
              CF_(16,16,17,18) CF_(17,17,18,19) CF_(18,18,19,20) CF_(19,19,20,21) \
              CF_(20,20,21,22) CF_(21,21,22,23) CF_(22,22,23,24) CF_(23,23,24,25) \
              CF_(24,24,25,26) CF_(25,25,26,27) CF_(26,26,27,28) CF_(27,27,28,29) \
              CF_(28,28,29,30) CF_(29,29,30,31) CF_(30,30,31,32) CF_(31,31,32,33)

// ---------------- K1: patch mean/std + dmax (transposed) + x3-ch2 bias init ----------------
__global__ __launch_bounds__(256) void k_patch(const float* __restrict__ x, const float* __restrict__ c1b,
                                               float* __restrict__ ws){
  float* x3    = ws + OFF_X3;
  float* dmaxT = ws + OFF_DMAX;        // [NPM][NB]
  int b = blockIdx.y;
  int chunk = blockIdx.x;              // 0..31, 2048 floats each
  const float* xr = x + (size_t)b*SEQ + chunk*2048;
  __shared__ float Ss[65], Qs[65], Dm[65];
  int w = threadIdx.x >> 6;
  int l = threadIdx.x & 63;
  #pragma unroll
  for (int i=0;i<2;i++){
    int seg = w*2 + i;
    int off = seg*256;
    float4 A = *(const float4*)(xr + off + l*4);
    float4 Bh = make_float4(0.f,0.f,0.f,0.f);
    if (l >= 56){
      int g = chunk*2048 + off + 256 + (l-56)*4;
      if (g + 3 < SEQ) Bh = *(const float4*)(xr + off + 256 + (l-56)*4);
    }
    int src = (l+8) & 63;
    float p0 = __shfl(A.x, src, 64), p1 = __shfl(A.y, src, 64),
          p2 = __shfl(A.z, src, 64), p3 = __shfl(A.w, src, 64);
    if (l >= 56){ p0=Bh.x; p1=Bh.y; p2=Bh.z; p3=Bh.w; }
    float s = (A.x+A.y)+(A.z+A.w);
    float q = fmaf(A.x,A.x, fmaf(A.y,A.y, fmaf(A.z,A.z, A.w*A.w)));
    float d = fmaxf(fmaxf(p0-A.x, p1-A.y), fmaxf(p2-A.z, p3-A.w));
    #pragma unroll
    for (int o=1;o<8;o<<=1){
      s += __shfl_xor(s,o,64);
      q += __shfl_xor(q,o,64);
      d  = fmaxf(d, __shfl_xor(d,o,64));
    }
    if ((l&7)==0){ int m = seg*8 + (l>>3); Ss[m]=s; Qs[m]=q; Dm[m]=d; }
  }
  if (w==0){
    float s=0.f,q=0.f,d=-1e30f;
    if (l < 8){
      int g = chunk*2048 + 2048 + l*4;
      if (g+3 < SEQ){
        float4 A = *(const float4*)(xr + 2048 + l*4);
        float4 P = make_float4(0.f,0.f,0.f,0.f);
        if (g+35 < SEQ) P = *(const float4*)(xr + 2048 + 32 + l*4);
        s = (A.x+A.y)+(A.z+A.w);
        q = fmaf(A.x,A.x, fmaf(A.y,A.y, fmaf(A.z,A.z, A.w*A.w)));
        d = fmaxf(fmaxf(P.x-A.x, P.y-A.y), fmaxf(P.z-A.z, P.w-A.w));
      }
    }
    #pragma unroll
    for (int o=1;o<8;o<<=1){
      s += __shfl_xor(s,o,64);
      q += __shfl_xor(q,o,64);
      d  = fmaxf(d, __shfl_xor(d,o,64));
    }
    if (l==0){ Ss[64]=s; Qs[64]=q; Dm[64]=d; }
  }
  __syncthreads();
  if (threadIdx.x < 64){
    int j = threadIdx.x;
    int p = chunk*64 + j;
    if (p < NP){
      float S = Ss[j]+Ss[j+1];
      float Q = Qs[j]+Qs[j+1];
      float mean = S*(1.0f/64.0f);
      float var  = (Q - S*mean)*(1.0f/63.0f);   // ddof=1
      x3[(b*3+0)*NP + p] = mean;
      x3[(b*3+1)*NP + p] = sqrtf(fmaxf(var,0.0f));
      x3[(b*3+2)*NP + p] = c1b[p];              // bias init (gemm atomically adds on top)
      if (p < NPM) dmaxT[(size_t)p*NB + b] = fmaxf(Dm[j], Dm[j+1]);
    }
  }
}

// ---------------- K_trW: conv1_w [NP][NPM] -> Wt [NPM][NP] ----------------
__global__ __launch_bounds__(256) void k_trW(const float* __restrict__ W, float* __restrict__ ws){
  float* Wt = ws + OFF_WT;
  __shared__ float t[64][65];
  int ko = blockIdx.x*64;
  int oo = blockIdx.y*64;
  int tx = threadIdx.x & 63, tw = threadIdx.x >> 6;
  #pragma unroll
  for (int r=0;r<16;r++){
    int rr = tw*16 + r;
    int o = oo + rr, k = ko + tx;
    t[rr][tx] = (o < NP && k < NPM) ? W[(size_t)o*NPM + k] : 0.f;
  }
  __syncthreads();
  #pragma unroll
  for (int r=0;r<16;r++){
    int rr = tw*16 + r;
    int k = ko + rr, o = oo + tx;
    if (k < NPM && o < NP) Wt[(size_t)k*NP + o] = t[tx][rr];
  }
}

// ---------------- K_wt: pack conv weights to [(i*3+tap)][c] ----------------
__global__ __launch_bounds__(256) void k_wt(const float* __restrict__ w2, const float* __restrict__ w3, float* __restrict__ ws){
  float* w2c = ws + OFF_W2C;
  float* w3c = ws + OFF_W3C;
  int t = blockIdx.x*256 + threadIdx.x;
  if (t < C1*3*C2){
    int r = t / C2, c = t - r*C2;          // r = i*3+tap
    int i = r/3, tap = r - i*3;
    w2c[t] = w2[(c*C1+i)*3 + tap];
  }
  if (t < C2*3*C3){
    int r = t / C3, c = t - r*C3;          // r = i*3+tap
    int i = r/3, tap = r - i*3;
    w3c[t] = w3[(c*C2+i)*3 + tap];
  }
}

// ---------------- K2: d2[b,o] += sum_k At[k,b]*Wt[k,o]  (no LDS, no barriers; k x2) ----------------
__global__ __launch_bounds__(256) void k_gemm(float* __restrict__ ws){
  const float* At = ws + OFF_DMAX;   // [NPM][NB]
  const float* Wt = ws + OFF_WT;     // [NPM][NP]
  float* x3 = ws + OFF_X3;
  int o  = blockIdx.x*64 + (threadIdx.x & 63);
  int w  = __builtin_amdgcn_readfirstlane(threadIdx.x >> 6);
  int bg = blockIdx.y*128 + w*32;
  int ks = blockIdx.z*256;
  int ke = min(ks+256, NPM);        // count is 256 or 254 — always even
  int oL = min(o, NP-1);
#define DG(c) float acc##c = 0.f;
  ACCS32(DG)
  const float* wp = Wt + oL;
  #pragma unroll 1
  for (int k=ks; k<ke; k+=2){
    float wv0 = wp[(size_t)k*NP];
    float wv1 = wp[(size_t)(k+1)*NP];
    const float* ar0 = At + (size_t)k*NB + bg;   // wave-uniform -> s_load
    const float* ar1 = ar0 + NB;
#define AR0(c) float av##c = ar0[c];
#define AR1(c) float bv##c = ar1[c];
    ACCS32(AR0)
    ACCS32(AR1)
#define FG2(c) { acc##c = fmaf(av##c, wv0, acc##c); acc##c = fmaf(bv##c, wv1, acc##c); }
    ACCS32(FG2)
  }
  if (o < NP){
    float* xp = x3 + 2*NP + o;
#define SG(c) atomicAdd(xp + (size_t)(bg+c)*3*NP, acc##c);
    ACCS32(SG)
  }
}

// ---------------- K3: conv1 (3->32, k=5, pad=2), plain ----------------
__global__ __launch_bounds__(256) void k_conv1(const float* __restrict__ w1, const float* __restrict__ b1, float* __restrict__ ws){
  const float* x3 = ws + OFF_X3;
  float* y1 = ws + OFF_Y1;
  int b = blockIdx.y;
  int l = blockIdx.x*256 + threadIdx.x;
  bool valid = (l < LEN1);
  float xin[3][5];
  #pragma unroll
  for (int i=0;i<3;i++){
    #pragma unroll
    for (int j=0;j<5;j++){
      int t = l + j - 2;
      xin[i][j] = (valid && t >= 0 && t < LEN1) ? x3[(b*3+i)*NP + t] : 0.f;
    }
  }
  #pragma unroll 8
  for (int c=0;c<C1;c++){
    float a = b1[c];
    #pragma unroll
    for (int i=0;i<3;i++){
      #pragma unroll
      for (int j=0;j<5;j++) a = fmaf(w1[(c*3+i)*5+j], xin[i][j], a);
    }
    if (valid) y1[(b*C1+c)*LEN1 + l] = a;
  }
}

// ---------------- stats (layer1): per-(b,c) sum/sumsq over y1 ----------------
__global__ __launch_bounds__(256) void k_stats(const float* __restrict__ y, float* __restrict__ ps,
                                               float* __restrict__ pq, int C, int L, int npart){
  int b = blockIdx.x, c = blockIdx.y;
  const float* p = y + ((size_t)b*C + c)*L;
  float s=0.f, q=0.f;
  for (int i=threadIdx.x; i<L; i+=256){ float v=p[i]; s+=v; q=fmaf(v,v,q); }
  __shared__ float rs[4], rq[4];
  RED6(s) RED6(q)
  int wid = threadIdx.x>>6, lane = threadIdx.x&63;
  if (lane==0){ rs[wid]=s; rq[wid]=q; }
  __syncthreads();
  if (threadIdx.x==0){
    ps[c*npart + b] = rs[0]+rs[1]+rs[2]+rs[3];
    pq[c*npart + b] = rq[0]+rq[1]+rq[2]+rq[3];
  }
}

// ---------------- finalize BN from partials ----------------
__global__ __launch_bounds__(256) void k_fin(const float* __restrict__ ps, const float* __restrict__ pq,
                                             const float* __restrict__ g, const float* __restrict__ be,
                                             float* __restrict__ stats, int C, int npart, double invN){
  int c = blockIdx.x;
  double s=0.0, q=0.0;
  for (int j=threadIdx.x; j<npart; j+=256){ s += (double)ps[c*npart+j]; q += (double)pq[c*npart+j]; }
  #pragma unroll
  for (int off=32; off; off>>=1){ s += __shfl_xor(s,off,64); q += __shfl_xor(q,off,64); }
  __shared__ double rs[4], rq[4];
  int wid = threadIdx.x>>6, lane=threadIdx.x&63;
  if (lane==0){ rs[wid]=s; rq[wid]=q; }
  __syncthreads();
  if (threadIdx.x==0){
    double S = rs[0]+rs[1]+rs[2]+rs[3];
    double Q = rq[0]+rq[1]+rq[2]+rq[3];
    double mean = S*invN;
    double var  = Q*invN - mean*mean;
    double a = (double)g[c] / sqrt(var + 1e-5);
    stats[c]   = (float)a;
    stats[C+c] = (float)((double)be[c] - mean*a);
  }
}

// ---------------- K4: pool1 — h1[b][i][m] = relu(bn1(max(y1[2m], y1[2m+1]))) ----------------
__global__ __launch_bounds__(256) void k_pool1(float* __restrict__ ws){
  const float* y1 = ws + OFF_Y1;
  const float* st = ws + OFF_S1;
  float* h1 = ws + OFF_H1;
  int b = blockIdx.z, i = blockIdx.y;
  int m = blockIdx.x*256 + threadIdx.x;
  if (m < LEN2){
    float sa = st[i], sb = st[C1+i];
    const float* yr = y1 + ((size_t)b*C1 + i)*LEN1 + 2*m;
    float v = fmaxf(yr[0], yr[1]);
    h1[((size_t)b*C1 + i)*LEN2 + m] = fmaxf(fmaf(sa, v, sb), 0.f);
  }
}

// ---------------- K5: conv2 (32->64) — lanes=channel; h via SMEM (grouped x2); weights via VMEM ----------------
__global__ __launch_bounds__(256) void k_conv2(const float* __restrict__ b2, float* __restrict__ ws){
  const float* h1  = ws + OFF_H1;     // [b][i][m], m<LEN2
  const float* w2c = ws + OFF_W2C;    // [(i*3+tap)][c]
  float* pmaxT = ws + OFF_PMAX;       // [b][m][c], m<LEN3
  float* ps = ws + OFF_PS;
  float* pq = ws + OFF_PQ;
  int b = blockIdx.y;
  int blk = blockIdx.x;               // 0..7 (128 positions each)
  int w  = __builtin_amdgcn_readfirstlane(threadIdx.x >> 6);
  int lane = threadIdx.x & 63;
  int p0 = blk*128 + w*32;            // wave-uniform
  int c  = lane;
#define AD2(p) float acc##p = b2[c];
  ACCS32(AD2)
  const float* hb = h1 + (size_t)b*C1*LEN2 + p0 - 1;
  const float* wb = w2c + c;
  #pragma unroll 1
  for (int i=0;i<C1;i+=2){
    const float* hpA = hb + (size_t)i*LEN2;      // wave-uniform -> s_load
    const float* hpB = hpA + LEN2;
    HS34(HLA)
    HS34(HLB)
    if (p0 == 0){ hh0 = 0.f; gg0 = 0.f; }
    if (p0 == 992){ hh32 = 0.f; hh33 = 0.f; gg32 = 0.f; gg33 = 0.f; }
    const float* wvA = wb + (i*3)*C2;            // per-lane coalesced VMEM
    const float* wvB = wb + ((i+1)*3)*C2;
    float w0a_ = wvA[0], w1a_ = wvA[C2], w2a_ = wvA[2*C2];
    float w0b_ = wvB[0], w1b_ = wvB[C2], w2b_ = wvB[2*C2];
    CONVSTEPS(CFA)
    CONVSTEPS(CFB)
  }
  int m0 = p0 >> 1;
  float* pp = pmaxT + ((size_t)b*LEN3 + m0)*C2 + c;
#define PST2(j,e,o) if (m0 + j < LEN3) pp[(size_t)(j)*C2] = fmaxf(acc##e, acc##o);
  POOL16(PST2)
  float ss = 0.f, qq = 0.f;
#define SAC2(p) if (p0 + p < LEN2){ ss += acc##p; qq = fmaf(acc##p, acc##p, qq); }
  ACCS32(SAC2)
  __shared__ float es[4][64], eq[4][64];
  es[w][lane] = ss; eq[w][lane] = qq;
  __syncthreads();
  if (w == 0){
    int pidx = b*8 + blk;
    float S = es[0][lane]+es[1][lane]+es[2][lane]+es[3][lane];
    float Q = eq[0][lane]+eq[1][lane]+eq[2][lane]+eq[3][lane];
    ps[lane*NPART + pidx] = S;
    pq[lane*NPART + pidx] = Q;
  }
}

// ---------------- K6: pool2t — h2[b][c][m] = relu(bn2(pmaxT[b][m][c]))  (LDS transpose) ----------------
__global__ __launch_bounds__(256) void k_pool2t(float* __restrict__ ws){
  const float* pm = ws + OFF_PMAX;   // [b][m][c]
  const float* st = ws + OFF_S2;
  float* h2 = ws + OFF_H2;           // [b][c][m]
  int b = blockIdx.y;
  int m0 = blockIdx.x*128;
  __shared__ float T[128][65];
  int c = threadIdx.x & 63;
  int r = threadIdx.x >> 6;          // 0..3
  float sa = st[c], sb = st[C2+c];
  for (int mm = r; mm < 128; mm += 4){
    int m = m0 + mm;
    float v = 0.f;
    if (m < LEN3) v = fmaxf(fmaf(sa, pm[((size_t)b*LEN3 + m)*C2 + c], sb), 0.f);
    T[mm][c] = v;
  }
  __syncthreads();
  int half = threadIdx.x >> 7;       // 0/1
  int mm = threadIdx.x & 127;
  int m = m0 + mm;
  if (m < LEN3){
    for (int cc = 0; cc < 32; cc++){
      int ch = cc*2 + half;
      h2[((size_t)b*C2 + ch)*LEN3 + m] = T[mm][ch];
    }
  }
}

// ---------------- K7: conv3 (64->128) — lanes=channel; h via SMEM (grouped x2); weights via VMEM ----------------
__global__ __launch_bounds__(256) void k_conv3(const float* __restrict__ b3, float* __restrict__ ws){
  const float* h2  = ws + OFF_H2;     // [b][i][m]
  const float* w3c = ws + OFF_W3C;    // [(i*3+tap)][c]
  float* y3t = ws + OFF_Y3T;          // [b][l][c]
  float* ps = ws + OFF_PS;
  float* pq = ws + OFF_PQ;
  int b = blockIdx.y;
  int blk = blockIdx.x;               // 0..7 (64 positions each)
  int w  = __builtin_amdgcn_readfirstlane(threadIdx.x >> 6);
  int lane = threadIdx.x & 63;
  int zh = w & 1, pg = w >> 1;
  int p0 = blk*64 + pg*32;            // uniform per wave
  int c  = zh*64 + lane;
#define AD3(p) float acc##p = b3[c];
  ACCS32(AD3)
  const float* hb = h2 + (size_t)b*C2*LEN3 + p0 - 1;
  const float* wb = w3c + c;
  #pragma unroll 1
  for (int i=0;i<C2;i+=2){
    const float* hpA = hb + (size_t)i*LEN3;      // wave-uniform -> s_load
    const float* hpB = hpA + LEN3;
    HS34(HLA)
    HS34(HLB)
    if (p0 == 0){ hh0 = 0.f; gg0 = 0.f; }
    if (p0 == 480){ hh32 = 0.f; hh33 = 0.f; gg32 = 0.f; gg33 = 0.f; }
    const float* wvA = wb + (i*3)*C3;            // per-lane coalesced VMEM
    const float* wvB = wb + ((i+1)*3)*C3;
    float w0a_ = wvA[0], w1a_ = wvA[C3], w2a_ = wvA[2*C3];
    float w0b_ = wvB[0], w1b_ = wvB[C3], w2b_ = wvB[2*C3];
    CONVSTEPS(CFA)
    CONVSTEPS(CFB)
  }
  float* yp = y3t + ((size_t)b*LEN3 + p0)*C3 + c;
#define STC(p) if (p0 + p < LEN3) yp[(size_t)(p)*C3] = acc##p;
  ACCS32(STC)
  float ss = 0.f, qq = 0.f;
#define SAC(p) if (p0 + p < LEN3){ ss += acc##p; qq = fmaf(acc##p, acc##p, qq); }
  ACCS32(SAC)
  __shared__ float es[4][64], eq[4][64];
  es[w][lane] = ss; eq[w][lane] = qq;
  __syncthreads();
  if (w < 2){
    int cc = (w & 1)*64 + lane;
    int pidx = b*8 + blk;
    ps[cc*NPART + pidx] = es[w][lane] + es[w+2][lane];
    pq[cc*NPART + pidx] = eq[w][lane] + eq[w+2][lane];
  }
}

// ---------------- K9: bn3+relu+mean over y3t [b][l][c] ----------------
__global__ __launch_bounds__(1024) void k_out(float* __restrict__ out, const float* __restrict__ ws){
  const float* y3t = ws + OFF_Y3T;
  const float* st = ws + OFF_S3;
  int b = blockIdx.x;
  int tid = threadIdx.x;
  int c = tid & 127, ph = tid >> 7;     // 8 phases
  float a = st[c], sh = st[C3+c];
  const float* yb = y3t + (size_t)b*LEN3*C3 + c;
  float s = 0.f;
  for (int l=ph; l<LEN3; l+=8) s += fmaxf(fmaf(a, yb[(size_t)l*C3], sh), 0.f);
  __shared__ float red[1024];
  red[tid] = s;
  __syncthreads();
  if (tid < 128){
    float t = 0.f;
    #pragma unroll
    for (int k=0;k<8;k++) t += red[k*128 + tid];
    out[b*C3 + tid] = t * (1.0f/511.0f);
  }
}

extern "C" void kernel_launch(void* const* d_in, const int* in_sizes, int n_in,
                              void* d_out, int out_size, void* d_ws, size_t ws_size,
                              hipStream_t stream) {
  const float* x   = (const float*)d_in[0];
  const float* c1w = (const float*)d_in[1];
  const float* c1b = (const float*)d_in[2];
  const float* w1  = (const float*)d_in[3];
  const float* b1  = (const float*)d_in[4];
  const float* g1  = (const float*)d_in[5];
  const float* be1 = (const float*)d_in[6];
  const float* w2  = (const float*)d_in[7];
  const float* b2  = (const float*)d_in[8];
  const float* g2  = (const float*)d_in[9];
  const float* be2 = (const float*)d_in[10];
  const float* w3  = (const float*)d_in[11];
  const float* b3  = (const float*)d_in[12];
  const float* g3  = (const float*)d_in[13];
  const float* be3 = (const float*)d_in[14];
  float* ws  = (float*)d_ws;
  float* out = (float*)d_out;

  hipLaunchKernelGGL(k_patch,  dim3(32,NB), dim3(256), 0, stream, x, c1b, ws);
  hipLaunchKernelGGL(k_trW,    dim3(32,32), dim3(256), 0, stream, c1w, ws);
  hipLaunchKernelGGL(k_wt,     dim3((C2*3*C3+255)/256), dim3(256), 0, stream, w2, w3, ws);
  hipLaunchKernelGGL(k_gemm,   dim3(32,2,8), dim3(256), 0, stream, ws);
  hipLaunchKernelGGL(k_conv1,  dim3(8,NB), dim3(256), 0, stream, w1, b1, ws);
  hipLaunchKernelGGL(k_stats,  dim3(NB,C1), dim3(256), 0, stream, ws+OFF_Y1, ws+OFF_PS, ws+OFF_PQ, C1, LEN1, NB);
  hipLaunchKernelGGL(k_fin,    dim3(C1), dim3(256), 0, stream, ws+OFF_PS, ws+OFF_PQ, g1, be1, ws+OFF_S1, C1, NB, 1.0/((double)NB*LEN1));
  hipLaunchKernelGGL(k_pool1,  dim3(4,C1,NB), dim3(256), 0, stream, ws);
  hipLaunchKernelGGL(k_conv2,  dim3(8,NB), dim3(256), 0, stream, b2, ws);
  hipLaunchKernelGGL(k_fin,    dim3(C2), dim3(256), 0, stream, ws+OFF_PS, ws+OFF_PQ, g2, be2, ws+OFF_S2, C2, NPART, 1.0/((double)NB*LEN2));
  hipLaunchKernelGGL(k_pool2t, dim3(4,NB), dim3(256), 0, stream, ws);
  hipLaunchKernelGGL(k_conv3,  dim3(8,NB), dim3(256), 0, stream, b3, ws);
  hipLaunchKernelGGL(k_fin,    dim3(C3), dim3(256), 0, stream, ws+OFF_PS, ws+OFF_PQ, g3, be3, ws+OFF_S3, C3, NPART, 1.0/((double)NB*LEN3));
  hipLaunchKernelGGL(k_out,    dim3(NB), dim3(1024), 0, stream, out, ws);
}

// Round 14
// 455.081 us; speedup vs baseline: 1.1056x; 1.0111x over previous
//
#include <hip/hip_runtime.h>
#include <math.h>

#define NB 256
#define SEQ 65536
#define NP 2047
#define NPM 2046
#define LEN1 2047
#define LEN2 1023
#define LEN3 511
#define C1 32
#define C2 64
#define C3 128
#define NPART 2048
#define LPAD 514   // h2T rows: pos -1 .. 512 (zero-padded ends)

// workspace offsets (floats). Region timeline:
//   Y2: gemm Wt -> h1 (pool1 out) -> h2T (bf16, p2bf out)
//   Y1: y1 (conv1 out) -> pmaxT (conv2 out) -> y3t (conv3m out)
#define OFF_X3   0
#define SZ_X3    (NB*3*NP)
#define OFF_DMAX (OFF_X3 + SZ_X3)
#define SZ_DMAX  (NB*NPM)
#define OFF_Y1   (OFF_DMAX + SZ_DMAX)
#define SZ_Y1    (NB*C1*LEN1)
#define OFF_Y2   (OFF_Y1 + SZ_Y1)
#define SZ_Y2    (NB*C2*LEN2)
#define OFF_S1   (OFF_Y2 + SZ_Y2)
#define OFF_S2   (OFF_S1 + 2*C1)
#define OFF_S3   (OFF_S2 + 2*C2)
#define OFF_W2C  (OFF_S3 + 2*C3)
#define OFF_W3B  (OFF_W2C + C1*C2*3)   // conv3 weights bf16 [tap][c][i]: 24576 halfs = 12288 floats
#define OFF_PS   (OFF_W3B + C2*C3*3)
#define OFF_PQ   (OFF_PS + C3*NPART)
#define OFF_WT   OFF_Y2   // gemm W^T (dead after gemm)
#define OFF_H1   OFF_Y2   // pooled bn1 activations [b][i][m], m<LEN2
#define OFF_H2T  OFF_Y2   // bf16 [b][LPAD][C2] (4.21M floats; h1 dead after conv2)
#define OFF_PMAX OFF_Y1   // conv2 pooled-raw out [b][m][c], m<LEN3
#define OFF_Y3T  OFF_Y1   // y3 transposed [b][l][c] (pmaxT dead after p2bf)

typedef __attribute__((ext_vector_type(8))) short short8;
typedef __attribute__((ext_vector_type(4))) float f32x4;

__device__ inline short f2bf(float f){
  union { float f; unsigned u; } x; x.f = f;
  unsigned r = x.u + 0x7FFF + ((x.u >> 16) & 1);   // RNE; inputs are normal finite
  return (short)(r >> 16);
}

#define ACCS16(X) X(0) X(1) X(2) X(3) X(4) X(5) X(6) X(7) \
                  X(8) X(9) X(10) X(11) X(12) X(13) X(14) X(15)
#define ACCS32(X) ACCS16(X) X(16) X(17) X(18) X(19) X(20) X(21) X(22) X(23) \
                  X(24) X(25) X(26) X(27) X(28) X(29) X(30) X(31)
#define HS34(X) X(0) X(1) X(2) X(3) X(4) X(5) X(6) X(7) X(8) X(9) X(10) X(11) \
                X(12) X(13) X(14) X(15) X(16) X(17) X(18) X(19) X(20) X(21) \
                X(22) X(23) X(24) X(25) X(26) X(27) X(28) X(29) X(30) X(31) X(32) X(33)
#define POOL16(X) X(0,0,1) X(1,2,3) X(2,4,5) X(3,6,7) X(4,8,9) X(5,10,11) X(6,12,13) X(7,14,15) \
                  X(8,16,17) X(9,18,19) X(10,20,21) X(11,22,23) X(12,24,25) X(13,26,27) X(14,28,29) X(15,30,31)

#define RED6(v) v += __shfl_xor(v,32,64); v += __shfl_xor(v,16,64); \
                v += __shfl_xor(v, 8,64); v += __shfl_xor(v, 4,64); \
                v += __shfl_xor(v, 2,64); v += __shfl_xor(v, 1,64);

// fp32 conv2 K-loop macros (R13 form — SMEM grouped x2)
#define HLA(j) float hh##j = hpA[j];
#define HLB(j) float gg##j = hpB[j];
#define CFA(p,j0,j1,j2) acc##p = fmaf(w0a_, hh##j0, acc##p); \
                        acc##p = fmaf(w1a_, hh##j1, acc##p); \
                        acc##p = fmaf(w2a_, hh##j2, acc##p);
#define CFB(p,j0,j1,j2) acc##p = fmaf(w0b_, gg##j0, acc##p); \
                        acc##p = fmaf(w1b_, gg##j1, acc##p); \
                        acc##p = fmaf(w2b_, gg##j2, acc##p);
#define CONVSTEPS(CF_) CF_(0,0,1,2)    CF_(1,1,2,3)    CF_(2,2,3,4)    CF_(3,3,4,5) \
              CF_(4,4,5,6)    CF_(5,5,6,7)    CF_(6,6,7,8)    CF_(7,7,8,9) \
              CF_(8,8,9,10)   CF_(9,9,10,11)  CF_(10,10,11,12) CF_(11,11,12,13) \
              CF_(12,12,13,14) CF_(13,13,14,15) CF_(14,14,15,16) CF_(15,15,16,17) \
              CF_(16,16,17,18) CF_(17,17,18,19) CF_(18,18,19,20) CF_(19,19,20,21) \
              CF_(20,20,21,22) CF_(21,21,22,23) CF_(22,22,23,24) CF_(23,23,24,25) \
              CF_(24,24,25,26) CF_(25,25,26,27) CF_(26,26,27,28) CF_(27,27,28,29) \
              CF_(28,28,29,30) CF_(29,29,30,31) CF_(30,30,31,32) CF_(31,31,32,33)

// ---------------- K1: patch mean/std + dmax (transposed) + x3-ch2 bias init ----------------
__global__ __launch_bounds__(256) void k_patch(const float* __restrict__ x, const float* __restrict__ c1b,
                                               float* __restrict__ ws){
  float* x3    = ws + OFF_X3;
  float* dmaxT = ws + OFF_DMAX;        // [NPM][NB]
  int b = blockIdx.y;
  int chunk = blockIdx.x;              // 0..31, 2048 floats each
  const float* xr = x + (size_t)b*SEQ + chunk*2048;
  __shared__ float Ss[65], Qs[65], Dm[65];
  int w = threadIdx.x >> 6;
  int l = threadIdx.x & 63;
  #pragma unroll
  for (int i=0;i<2;i++){
    int seg = w*2 + i;
    int off = seg*256;
    float4 A = *(const float4*)(xr + off + l*4);
    float4 Bh = make_float4(0.f,0.f,0.f,0.f);
    if (l >= 56){
      int g = chunk*2048 + off + 256 + (l-56)*4;
      if (g + 3 < SEQ) Bh = *(const float4*)(xr + off + 256 + (l-56)*4);
    }
    int src = (l+8) & 63;
    float p0 = __shfl(A.x, src, 64), p1 = __shfl(A.y, src, 64),
          p2 = __shfl(A.z, src, 64), p3 = __shfl(A.w, src, 64);
    if (l >= 56){ p0=Bh.x; p1=Bh.y; p2=Bh.z; p3=Bh.w; }
    float s = (A.x+A.y)+(A.z+A.w);
    float q = fmaf(A.x,A.x, fmaf(A.y,A.y, fmaf(A.z,A.z, A.w*A.w)));
    float d = fmaxf(fmaxf(p0-A.x, p1-A.y), fmaxf(p2-A.z, p3-A.w));
    #pragma unroll
    for (int o=1;o<8;o<<=1){
      s += __shfl_xor(s,o,64);
      q += __shfl_xor(q,o,64);
      d  = fmaxf(d, __shfl_xor(d,o,64));
    }
    if ((l&7)==0){ int m = seg*8 + (l>>3); Ss[m]=s; Qs[m]=q; Dm[m]=d; }
  }
  if (w==0){
    float s=0.f,q=0.f,d=-1e30f;
    if (l < 8){
      int g = chunk*2048 + 2048 + l*4;
      if (g+3 < SEQ){
        float4 A = *(const float4*)(xr + 2048 + l*4);
        float4 P = make_float4(0.f,0.f,0.f,0.f);
        if (g+35 < SEQ) P = *(const float4*)(xr + 2048 + 32 + l*4);
        s = (A.x+A.y)+(A.z+A.w);
        q = fmaf(A.x,A.x, fmaf(A.y,A.y, fmaf(A.z,A.z, A.w*A.w)));
        d = fmaxf(fmaxf(P.x-A.x, P.y-A.y), fmaxf(P.z-A.z, P.w-A.w));
      }
    }
    #pragma unroll
    for (int o=1;o<8;o<<=1){
      s += __shfl_xor(s,o,64);
      q += __shfl_xor(q,o,64);
      d  = fmaxf(d, __shfl_xor(d,o,64));
    }
    if (l==0){ Ss[64]=s; Qs[64]=q; Dm[64]=d; }
  }
  __syncthreads();
  if (threadIdx.x < 64){
    int j = threadIdx.x;
    int p = chunk*64 + j;
    if (p < NP){
      float S = Ss[j]+Ss[j+1];
      float Q = Qs[j]+Qs[j+1];
      float mean = S*(1.0f/64.0f);
      float var  = (Q - S*mean)*(1.0f/63.0f);   // ddof=1
      x3[(b*3+0)*NP + p] = mean;
      x3[(b*3+1)*NP + p] = sqrtf(fmaxf(var,0.0f));
      x3[(b*3+2)*NP + p] = c1b[p];              // bias init (gemm atomically adds on top)
      if (p < NPM) dmaxT[(size_t)p*NB + b] = fmaxf(Dm[j], Dm[j+1]);
    }
  }
}

// ---------------- K_trW: conv1_w [NP][NPM] -> Wt [NPM][NP] ----------------
__global__ __launch_bounds__(256) void k_trW(const float* __restrict__ W, float* __restrict__ ws){
  float* Wt = ws + OFF_WT;
  __shared__ float t[64][65];
  int ko = blockIdx.x*64;
  int oo = blockIdx.y*64;
  int tx = threadIdx.x & 63, tw = threadIdx.x >> 6;
  #pragma unroll
  for (int r=0;r<16;r++){
    int rr = tw*16 + r;
    int o = oo + rr, k = ko + tx;
    t[rr][tx] = (o < NP && k < NPM) ? W[(size_t)o*NPM + k] : 0.f;
  }
  __syncthreads();
  #pragma unroll
  for (int r=0;r<16;r++){
    int rr = tw*16 + r;
    int k = ko + rr, o = oo + tx;
    if (k < NPM && o < NP) Wt[(size_t)k*NP + o] = t[tx][rr];
  }
}

// ---------------- K_wt: pack conv2 weights fp32 [(i*3+tap)][c]; conv3 weights bf16 [tap][c][i] ----------------
__global__ __launch_bounds__(256) void k_wt(const float* __restrict__ w2, const float* __restrict__ w3, float* __restrict__ ws){
  float* w2c = ws + OFF_W2C;
  short* w3b = (short*)(ws + OFF_W3B);
  int t = blockIdx.x*256 + threadIdx.x;
  if (t < C1*3*C2){
    int r = t / C2, c = t - r*C2;          // r = i*3+tap
    int i = r/3, tap = r - i*3;
    w2c[t] = w2[(c*C1+i)*3 + tap];
  }
  if (t < 3*C3*C2){
    int tap = t / (C3*C2);
    int r = t - tap*(C3*C2);
    int c = r / C2, i = r - c*C2;
    w3b[(tap*C3 + c)*C2 + i] = f2bf(w3[(c*C2+i)*3 + tap]);
  }
}

// ---------------- K2: d2[b,o] += sum_k At[k,b]*Wt[k,o]  (no LDS, no barriers; k x2) ----------------
__global__ __launch_bounds__(256) void k_gemm(float* __restrict__ ws){
  const float* At = ws + OFF_DMAX;   // [NPM][NB]
  const float* Wt = ws + OFF_WT;     // [NPM][NP]
  float* x3 = ws + OFF_X3;
  int o  = blockIdx.x*64 + (threadIdx.x & 63);
  int w  = __builtin_amdgcn_readfirstlane(threadIdx.x >> 6);
  int bg = blockIdx.y*128 + w*32;
  int ks = blockIdx.z*256;
  int ke = min(ks+256, NPM);        // count is 256 or 254 — always even
  int oL = min(o, NP-1);
#define DG(c) float acc##c = 0.f;
  ACCS32(DG)
  const float* wp = Wt + oL;
  #pragma unroll 1
  for (int k=ks; k<ke; k+=2){
    float wv0 = wp[(size_t)k*NP];
    float wv1 = wp[(size_t)(k+1)*NP];
    const float* ar0 = At + (size_t)k*NB + bg;   // wave-uniform -> s_load
    const float* ar1 = ar0 + NB;
#define AR0(c) float av##c = ar0[c];
#define AR1(c) float bv##c = ar1[c];
    ACCS32(AR0)
    ACCS32(AR1)
#define FG2(c) { acc##c = fmaf(av##c, wv0, acc##c); acc##c = fmaf(bv##c, wv1, acc##c); }
    ACCS32(FG2)
  }
  if (o < NP){
    float* xp = x3 + 2*NP + o;
#define SG(c) atomicAdd(xp + (size_t)(bg+c)*3*NP, acc##c);
    ACCS32(SG)
  }
}

// ---------------- K3: conv1 (3->32, k=5, pad=2), plain ----------------
__global__ __launch_bounds__(256) void k_conv1(const float* __restrict__ w1, const float* __restrict__ b1, float* __restrict__ ws){
  const float* x3 = ws + OFF_X3;
  float* y1 = ws + OFF_Y1;
  int b = blockIdx.y;
  int l = blockIdx.x*256 + threadIdx.x;
  bool valid = (l < LEN1);
  float xin[3][5];
  #pragma unroll
  for (int i=0;i<3;i++){
    #pragma unroll
    for (int j=0;j<5;j++){
      int t = l + j - 2;
      xin[i][j] = (valid && t >= 0 && t < LEN1) ? x3[(b*3+i)*NP + t] : 0.f;
    }
  }
  #pragma unroll 8
  for (int c=0;c<C1;c++){
    float a = b1[c];
    #pragma unroll
    for (int i=0;i<3;i++){
      #pragma unroll
      for (int j=0;j<5;j++) a = fmaf(w1[(c*3+i)*5+j], xin[i][j], a);
    }
    if (valid) y1[(b*C1+c)*LEN1 + l] = a;
  }
}

// ---------------- stats (layer1): per-(b,c) sum/sumsq over y1 ----------------
__global__ __launch_bounds__(256) void k_stats(const float* __restrict__ y, float* __restrict__ ps,
                                               float* __restrict__ pq, int C, int L, int npart){
  int b = blockIdx.x, c = blockIdx.y;
  const float* p = y + ((size_t)b*C + c)*L;
  float s=0.f, q=0.f;
  for (int i=threadIdx.x; i<L; i+=256){ float v=p[i]; s+=v; q=fmaf(v,v,q); }
  __shared__ float rs[4], rq[4];
  RED6(s) RED6(q)
  int wid = threadIdx.x>>6, lane = threadIdx.x&63;
  if (lane==0){ rs[wid]=s; rq[wid]=q; }
  __syncthreads();
  if (threadIdx.x==0){
    ps[c*npart + b] = rs[0]+rs[1]+rs[2]+rs[3];
    pq[c*npart + b] = rq[0]+rq[1]+rq[2]+rq[3];
  }
}

// ---------------- finalize BN from partials ----------------
__global__ __launch_bounds__(256) void k_fin(const float* __restrict__ ps, const float* __restrict__ pq,
                                             const float* __restrict__ g, const float* __restrict__ be,
                                             float* __restrict__ stats, int C, int npart, double invN){
  int c = blockIdx.x;
  double s=0.0, q=0.0;
  for (int j=threadIdx.x; j<npart; j+=256){ s += (double)ps[c*npart+j]; q += (double)pq[c*npart+j]; }
  #pragma unroll
  for (int off=32; off; off>>=1){ s += __shfl_xor(s,off,64); q += __shfl_xor(q,off,64); }
  __shared__ double rs[4], rq[4];
  int wid = threadIdx.x>>6, lane=threadIdx.x&63;
  if (lane==0){ rs[wid]=s; rq[wid]=q; }
  __syncthreads();
  if (threadIdx.x==0){
    double S = rs[0]+rs[1]+rs[2]+rs[3];
    double Q = rq[0]+rq[1]+rq[2]+rq[3];
    double mean = S*invN;
    double var  = Q*invN - mean*mean;
    double a = (double)g[c] / sqrt(var + 1e-5);
    stats[c]   = (float)a;
    stats[C+c] = (float)((double)be[c] - mean*a);
  }
}

// ---------------- K4: pool1 — h1[b][i][m] = relu(bn1(max(y1[2m], y1[2m+1]))) ----------------
__global__ __launch_bounds__(256) void k_pool1(float* __restrict__ ws){
  const float* y1 = ws + OFF_Y1;
  const float* st = ws + OFF_S1;
  float* h1 = ws + OFF_H1;
  int b = blockIdx.z, i = blockIdx.y;
  int m = blockIdx.x*256 + threadIdx.x;
  if (m < LEN2){
    float sa = st[i], sb = st[C1+i];
    const float* yr = y1 + ((size_t)b*C1 + i)*LEN1 + 2*m;
    float v = fmaxf(yr[0], yr[1]);
    h1[((size_t)b*C1 + i)*LEN2 + m] = fmaxf(fmaf(sa, v, sb), 0.f);
  }
}

// ---------------- K5: conv2 (32->64) — lanes=channel; h via SMEM (grouped x2); weights via VMEM ----------------
__global__ __launch_bounds__(256) void k_conv2(const float* __restrict__ b2, float* __restrict__ ws){
  const float* h1  = ws + OFF_H1;     // [b][i][m], m<LEN2
  const float* w2c = ws + OFF_W2C;    // [(i*3+tap)][c]
  float* pmaxT = ws + OFF_PMAX;       // [b][m][c], m<LEN3
  float* ps = ws + OFF_PS;
  float* pq = ws + OFF_PQ;
  int b = blockIdx.y;
  int blk = blockIdx.x;               // 0..7 (128 positions each)
  int w  = __builtin_amdgcn_readfirstlane(threadIdx.x >> 6);
  int lane = threadIdx.x & 63;
  int p0 = blk*128 + w*32;            // wave-uniform
  int c  = lane;
#define AD2(p) float acc##p = b2[c];
  ACCS32(AD2)
  const float* hb = h1 + (size_t)b*C1*LEN2 + p0 - 1;
  const float* wb = w2c + c;
  #pragma unroll 1
  for (int i=0;i<C1;i+=2){
    const float* hpA = hb + (size_t)i*LEN2;      // wave-uniform -> s_load
    const float* hpB = hpA + LEN2;
    HS34(HLA)
    HS34(HLB)
    if (p0 == 0){ hh0 = 0.f; gg0 = 0.f; }
    if (p0 == 992){ hh32 = 0.f; hh33 = 0.f; gg32 = 0.f; gg33 = 0.f; }
    const float* wvA = wb + (i*3)*C2;            // per-lane coalesced VMEM
    const float* wvB = wb + ((i+1)*3)*C2;
    float w0a_ = wvA[0], w1a_ = wvA[C2], w2a_ = wvA[2*C2];
    float w0b_ = wvB[0], w1b_ = wvB[C2], w2b_ = wvB[2*C2];
    CONVSTEPS(CFA)
    CONVSTEPS(CFB)
  }
  int m0 = p0 >> 1;
  float* pp = pmaxT + ((size_t)b*LEN3 + m0)*C2 + c;
#define PST2(j,e,o) if (m0 + j < LEN3) pp[(size_t)(j)*C2] = fmaxf(acc##e, acc##o);
  POOL16(PST2)
  float ss = 0.f, qq = 0.f;
#define SAC2(p) if (p0 + p < LEN2){ ss += acc##p; qq = fmaf(acc##p, acc##p, qq); }
  ACCS32(SAC2)
  __shared__ float es[4][64], eq[4][64];
  es[w][lane] = ss; eq[w][lane] = qq;
  __syncthreads();
  if (w == 0){
    int pidx = b*8 + blk;
    float S = es[0][lane]+es[1][lane]+es[2][lane]+es[3][lane];
    float Q = eq[0][lane]+eq[1][lane]+eq[2][lane]+eq[3][lane];
    ps[lane*NPART + pidx] = S;
    pq[lane*NPART + pidx] = Q;
  }
}

// ---------------- K6: p2bf — h2T[b][m+1][c] = bf16(relu(bn2(pmaxT[b][m][c]))); zero pad rows ----------------
// pmaxT is already [m][c]-major: no transpose needed for the MFMA B layout.
__global__ __launch_bounds__(256) void k_p2bf(float* __restrict__ ws){
  const float* pm = ws + OFF_PMAX;   // [b][m][c]
  const float* st = ws + OFF_S2;
  short* h2t = (short*)(ws + OFF_H2T); // [b][LPAD][C2], row r = position r-1
  int b = blockIdx.y;
  int idx = blockIdx.x*256 + threadIdx.x;
  if (idx < LEN3*C2){
    int m = idx >> 6, c = idx & 63;
    float v = fmaxf(fmaf(st[c], pm[((size_t)b*LEN3 + m)*C2 + c], st[C2+c]), 0.f);
    h2t[((size_t)b*LPAD + m + 1)*C2 + c] = f2bf(v);
  } else {
    int zr = idx - LEN3*C2;          // 192 pad slots: rows 0, 512, 513
    if (zr < 3*C2){
      int rsel = zr >> 6, c = zr & 63;
      int row = (rsel == 0) ? 0 : (511 + rsel);   // 0, 512, 513
      h2t[((size_t)b*LPAD + row)*C2 + c] = 0;
    }
  }
}

// ---------------- K7: conv3 via MFMA bf16 — y3[c][l] = sum_tap W_tap · h2[.][l+tap-1] ----------------
// Per wave: 4 c-tiles x 1 l-tile; 3 taps x 2 K-steps = 24 MFMAs; zero LDS/SMEM/barriers.
// Layouts (HW-verified): A[m=lane&15][k=quad*8+j], B[k=quad*8+j][n=lane&15],
// D[row=quad*4+reg][col=lane&15].  A=W (m=c), B=h2T rows (n=l).
__global__ __launch_bounds__(256) void k_conv3m(const float* __restrict__ b3, float* __restrict__ ws){
  const short* h2t = (const short*)(ws + OFF_H2T);  // [b][LPAD][C2]
  const short* w3b = (const short*)(ws + OFF_W3B);  // [tap][C3][C2]
  float* y3t = ws + OFF_Y3T;                        // [b][l][c]
  int b  = blockIdx.z;
  int cg = blockIdx.y;                 // 0/1: 64-channel half
  int wid = __builtin_amdgcn_readfirstlane(threadIdx.x >> 6);
  int lane = threadIdx.x & 63;
  int lt = blockIdx.x*4 + wid;         // 0..31
  int ln = lane & 15, kq = lane >> 4;
  int l  = lt*16 + ln;                 // output position (col); l==511 discarded
  int cb = cg*64;
  f32x4 acc0 = *(const f32x4*)(b3 + cb +  0 + kq*4);   // bias in C-frag (broadcast over n)
  f32x4 acc1 = *(const f32x4*)(b3 + cb + 16 + kq*4);
  f32x4 acc2 = *(const f32x4*)(b3 + cb + 32 + kq*4);
  f32x4 acc3 = *(const f32x4*)(b3 + cb + 48 + kq*4);
  const short* hB = h2t + ((size_t)b*LPAD + l)*C2 + kq*8;          // + tap*C2 + s*32
  const short* wA = w3b + ((size_t)(cb + ln))*C2 + kq*8;           // + tap*C3*C2 + ct*16*C2 + s*32
  #pragma unroll
  for (int t=0;t<3;t++){
    #pragma unroll
    for (int s=0;s<2;s++){
      short8 bv = *(const short8*)(hB + t*C2 + s*32);
      short8 a0 = *(const short8*)(wA + t*C3*C2 +    0 + s*32);
      short8 a1 = *(const short8*)(wA + t*C3*C2 + 1024 + s*32);
      short8 a2 = *(const short8*)(wA + t*C3*C2 + 2048 + s*32);
      short8 a3 = *(const short8*)(wA + t*C3*C2 + 3072 + s*32);
      acc0 = __builtin_amdgcn_mfma_f32_16x16x32_bf16(a0, bv, acc0, 0, 0, 0);
      acc1 = __builtin_amdgcn_mfma_f32_16x16x32_bf16(a1, bv, acc1, 0, 0, 0);
      acc2 = __builtin_amdgcn_mfma_f32_16x16x32_bf16(a2, bv, acc2, 0, 0, 0);
      acc3 = __builtin_amdgcn_mfma_f32_16x16x32_bf16(a3, bv, acc3, 0, 0, 0);
    }
  }
  if (l < LEN3){
    float* yp = y3t + ((size_t)b*LEN3 + l)*C3 + cb + kq*4;
    *(f32x4*)(yp +  0) = acc0;
    *(f32x4*)(yp + 16) = acc1;
    *(f32x4*)(yp + 32) = acc2;
    *(f32x4*)(yp + 48) = acc3;
  }
}

// ---------------- K8: stats3 — per-channel sum/sumsq over y3t [b][l][c] ----------------
__global__ __launch_bounds__(1024) void k_stats3(float* __restrict__ ws){
  const float* y3t = ws + OFF_Y3T;
  float* ps = ws + OFF_PS;
  float* pq = ws + OFF_PQ;
  int b = blockIdx.x;
  int tid = threadIdx.x;
  int c = tid & 127, ph = tid >> 7;    // 8 phases
  const float* yb = y3t + (size_t)b*LEN3*C3 + c;
  float s = 0.f, q = 0.f;
  for (int l=ph; l<LEN3; l+=8){ float v = yb[(size_t)l*C3]; s += v; q = fmaf(v,v,q); }
  __shared__ float rs[1024], rq[1024];
  rs[tid] = s; rq[tid] = q;
  __syncthreads();
  if (tid < 128){
    float S = 0.f, Q = 0.f;
    #pragma unroll
    for (int k=0;k<8;k++){ S += rs[k*128 + tid]; Q += rq[k*128 + tid]; }
    ps[tid*NB + b] = S;
    pq[tid*NB + b] = Q;
  }
}

// ---------------- K9: bn3+relu+mean over y3t [b][l][c] ----------------
__global__ __launch_bounds__(1024) void k_out(float* __restrict__ out, const float* __restrict__ ws){
  const float* y3t = ws + OFF_Y3T;
  const float* st = ws + OFF_S3;
  int b = blockIdx.x;
  int tid = threadIdx.x;
  int c = tid & 127, ph = tid >> 7;     // 8 phases
  float a = st[c], sh = st[C3+c];
  const float* yb = y3t + (size_t)b*LEN3*C3 + c;
  float s = 0.f;
  for (int l=ph; l<LEN3; l+=8) s += fmaxf(fmaf(a, yb[(size_t)l*C3], sh), 0.f);
  __shared__ float red[1024];
  red[tid] = s;
  __syncthreads();
  if (tid < 128){
    float t = 0.f;
    #pragma unroll
    for (int k=0;k<8;k++) t += red[k*128 + tid];
    out[b*C3 + tid] = t * (1.0f/511.0f);
  }
}

extern "C" void kernel_launch(void* const* d_in, const int* in_sizes, int n_in,
                              void* d_out, int out_size, void* d_ws, size_t ws_size,
                              hipStream_t stream) {
  const float* x   = (const float*)d_in[0];
  const float* c1w = (const float*)d_in[1];
  const float* c1b = (const float*)d_in[2];
  const float* w1  = (const float*)d_in[3];
  const float* b1  = (const float*)d_in[4];
  const float* g1  = (const float*)d_in[5];
  const float* be1 = (const float*)d_in[6];
  const float* w2  = (const float*)d_in[7];
  const float* b2  = (const float*)d_in[8];
  const float* g2  = (const float*)d_in[9];
  const float* be2 = (const float*)d_in[10];
  const float* w3  = (const float*)d_in[11];
  const float* b3  = (const float*)d_in[12];
  const float* g3  = (const float*)d_in[13];
  const float* be3 = (const float*)d_in[14];
  float* ws  = (float*)d_ws;
  float* out = (float*)d_out;

  hipLaunchKernelGGL(k_patch,  dim3(32,NB), dim3(256), 0, stream, x, c1b, ws);
  hipLaunchKernelGGL(k_trW,    dim3(32,32), dim3(256), 0, stream, c1w, ws);
  hipLaunchKernelGGL(k_wt,     dim3((3*C3*C2+255)/256), dim3(256), 0, stream, w2, w3, ws);
  hipLaunchKernelGGL(k_gemm,   dim3(32,2,8), dim3(256), 0, stream, ws);
  hipLaunchKernelGGL(k_conv1,  dim3(8,NB), dim3(256), 0, stream, w1, b1, ws);
  hipLaunchKernelGGL(k_stats,  dim3(NB,C1), dim3(256), 0, stream, ws+OFF_Y1, ws+OFF_PS, ws+OFF_PQ, C1, LEN1, NB);
  hipLaunchKernelGGL(k_fin,    dim3(C1), dim3(256), 0, stream, ws+OFF_PS, ws+OFF_PQ, g1, be1, ws+OFF_S1, C1, NB, 1.0/((double)NB*LEN1));
  hipLaunchKernelGGL(k_pool1,  dim3(4,C1,NB), dim3(256), 0, stream, ws);
  hipLaunchKernelGGL(k_conv2,  dim3(8,NB), dim3(256), 0, stream, b2, ws);
  hipLaunchKernelGGL(k_fin,    dim3(C2), dim3(256), 0, stream, ws+OFF_PS, ws+OFF_PQ, g2, be2, ws+OFF_S2, C2, NPART, 1.0/((double)NB*LEN2));
  hipLaunchKernelGGL(k_p2bf,   dim3((LEN3*C2+3*C2+255)/256, NB), dim3(256), 0, stream, ws);
  hipLaunchKernelGGL(k_conv3m, dim3(8,2,NB), dim3(256), 0, stream, b3, ws);
  hipLaunchKernelGGL(k_stats3, dim3(NB), dim3(1024), 0, stream, ws);
  hipLaunchKernelGGL(k_fin,    dim3(C3), dim3(256), 0, stream, ws+OFF_PS, ws+OFF_PQ, g3, be3, ws+OFF_S3, C3, NB, 1.0/((double)NB*LEN3));
  hipLaunchKernelGGL(k_out,    dim3(NB), dim3(1024), 0, stream, out, ws);
}

// Round 15
// 400.217 us; speedup vs baseline: 1.2572x; 1.1371x over previous
//
#include <hip/hip_runtime.h>
#include <math.h>

#define NB 256
#define SEQ 65536
#define NP 2047
#define NPM 2046
#define KPAD 2048  // gemm K padded (bf16 operands zero-filled at k=2046,2047)
#define LEN1 2047
#define LEN2 1023
#define LEN3 511
#define C1 32
#define C2 64
#define C3 128
#define NPART 2048
#define LPAD 514   // h2T rows: pos -1 .. 512 (zero-padded ends)

// workspace offsets (floats). Region timeline:
//   Y2: gemm Wb (bf16) -> h1 (pool1 out) -> h2T (bf16, p2bf out)
//   Y1: y1 (conv1 out) -> pmaxT (conv2 out) -> y3t (conv3m out)
//   DMAX: dmax bf16 [b][KPAD]
#define OFF_X3   0
#define SZ_X3    (NB*3*NP)
#define OFF_DMAX (OFF_X3 + SZ_X3)
#define SZ_DMAX  (NB*NPM)
#define OFF_Y1   (OFF_DMAX + SZ_DMAX)
#define SZ_Y1    (NB*C1*LEN1)
#define OFF_Y2   (OFF_Y1 + SZ_Y1)
#define SZ_Y2    (NB*C2*LEN2)
#define OFF_S1   (OFF_Y2 + SZ_Y2)
#define OFF_S2   (OFF_S1 + 2*C1)
#define OFF_S3   (OFF_S2 + 2*C2)
#define OFF_W2C  (OFF_S3 + 2*C3)
#define OFF_W3B  (OFF_W2C + C1*C2*3)   // conv3 weights bf16 [tap][c][i]
#define OFF_PS   (OFF_W3B + C2*C3*3)
#define OFF_PQ   (OFF_PS + C3*NPART)
#define OFF_WB   OFF_Y2   // gemm W bf16 [NP][KPAD] (dead after gemm)
#define OFF_H1   OFF_Y2   // pooled bn1 activations [b][i][m], m<LEN2
#define OFF_H2T  OFF_Y2   // bf16 [b][LPAD][C2] (h1 dead after conv2)
#define OFF_PMAX OFF_Y1   // conv2 pooled-raw out [b][m][c], m<LEN3
#define OFF_Y3T  OFF_Y1   // y3 transposed [b][l][c] (pmaxT dead after p2bf)

typedef __attribute__((ext_vector_type(8))) short short8;
typedef __attribute__((ext_vector_type(4))) float f32x4;

__device__ inline short f2bf(float f){
  union { float f; unsigned u; } x; x.f = f;
  unsigned r = x.u + 0x7FFF + ((x.u >> 16) & 1);   // RNE; inputs are normal finite
  return (short)(r >> 16);
}

#define ACCS16(X) X(0) X(1) X(2) X(3) X(4) X(5) X(6) X(7) \
                  X(8) X(9) X(10) X(11) X(12) X(13) X(14) X(15)
#define ACCS32(X) ACCS16(X) X(16) X(17) X(18) X(19) X(20) X(21) X(22) X(23) \
                  X(24) X(25) X(26) X(27) X(28) X(29) X(30) X(31)
#define HS34(X) X(0) X(1) X(2) X(3) X(4) X(5) X(6) X(7) X(8) X(9) X(10) X(11) \
                X(12) X(13) X(14) X(15) X(16) X(17) X(18) X(19) X(20) X(21) \
                X(22) X(23) X(24) X(25) X(26) X(27) X(28) X(29) X(30) X(31) X(32) X(33)
#define POOL16(X) X(0,0,1) X(1,2,3) X(2,4,5) X(3,6,7) X(4,8,9) X(5,10,11) X(6,12,13) X(7,14,15) \
                  X(8,16,17) X(9,18,19) X(10,20,21) X(11,22,23) X(12,24,25) X(13,26,27) X(14,28,29) X(15,30,31)

#define RED6(v) v += __shfl_xor(v,32,64); v += __shfl_xor(v,16,64); \
                v += __shfl_xor(v, 8,64); v += __shfl_xor(v, 4,64); \
                v += __shfl_xor(v, 2,64); v += __shfl_xor(v, 1,64);

// fp32 conv2 K-loop macros (R13 form — SMEM grouped x2)
#define HLA(j) float hh##j = hpA[j];
#define HLB(j) float gg##j = hpB[j];
#define CFA(p,j0,j1,j2) acc##p = fmaf(w0a_, hh##j0, acc##p); \
                        acc##p = fmaf(w1a_, hh##j1, acc##p); \
                        acc##p = fmaf(w2a_, hh##j2, acc##p);
#define CFB(p,j0,j1,j2) acc##p = fmaf(w0b_, gg##j0, acc##p); \
                        acc##p = fmaf(w1b_, gg##j1, acc##p); \
                        acc##p = fmaf(w2b_, gg##j2, acc##p);
#define CONVSTEPS(CF_) CF_(0,0,1,2)    CF_(1,1,2,3)    CF_(2,2,3,4)    CF_(3,3,4,5) \
              CF_(4,4,5,6)    CF_(5,5,6,7)    CF_(6,6,7,8)    CF_(7,7,8,9) \
              CF_(8,8,9,10)   CF_(9,9,10,11)  CF_(10,10,11,12) CF_(11,11,12,13) \
              CF_(12,12,13,14) CF_(13,13,14,15) CF_(14,14,15,16) CF_(15,15,16,17) \
              CF_(16,16,17,18) CF_(17,17,18,19) CF_(18,18,19,20) CF_(19,19,20,21) \
              CF_(20,20,21,22) CF_(21,21,22,23) CF_(22,22,23,24) CF_(23,23,24,25) \
              CF_(24,24,25,26) CF_(25,25,26,27) CF_(26,26,27,28) CF_(27,27,28,29) \
              CF_(28,28,29,30) CF_(29,29,30,31) CF_(30,30,31,32) CF_(31,31,32,33)

// ---------------- K1: patch mean/std + dmax (bf16, [b][KPAD]) + x3-ch2 bias init ----------------
__global__ __launch_bounds__(256) void k_patch(const float* __restrict__ x, const float* __restrict__ c1b,
                                               float* __restrict__ ws){
  float* x3    = ws + OFF_X3;
  short* dmaxB = (short*)(ws + OFF_DMAX);   // bf16 [NB][KPAD], zero-padded k>=NPM
  int b = blockIdx.y;
  int chunk = blockIdx.x;              // 0..31, 2048 floats each
  const float* xr = x + (size_t)b*SEQ + chunk*2048;
  __shared__ float Ss[65], Qs[65], Dm[65];
  int w = threadIdx.x >> 6;
  int l = threadIdx.x & 63;
  #pragma unroll
  for (int i=0;i<2;i++){
    int seg = w*2 + i;
    int off = seg*256;
    float4 A = *(const float4*)(xr + off + l*4);
    float4 Bh = make_float4(0.f,0.f,0.f,0.f);
    if (l >= 56){
      int g = chunk*2048 + off + 256 + (l-56)*4;
      if (g + 3 < SEQ) Bh = *(const float4*)(xr + off + 256 + (l-56)*4);
    }
    int src = (l+8) & 63;
    float p0 = __shfl(A.x, src, 64), p1 = __shfl(A.y, src, 64),
          p2 = __shfl(A.z, src, 64), p3 = __shfl(A.w, src, 64);
    if (l >= 56){ p0=Bh.x; p1=Bh.y; p2=Bh.z; p3=Bh.w; }
    float s = (A.x+A.y)+(A.z+A.w);
    float q = fmaf(A.x,A.x, fmaf(A.y,A.y, fmaf(A.z,A.z, A.w*A.w)));
    float d = fmaxf(fmaxf(p0-A.x, p1-A.y), fmaxf(p2-A.z, p3-A.w));
    #pragma unroll
    for (int o=1;o<8;o<<=1){
      s += __shfl_xor(s,o,64);
      q += __shfl_xor(q,o,64);
      d  = fmaxf(d, __shfl_xor(d,o,64));
    }
    if ((l&7)==0){ int m = seg*8 + (l>>3); Ss[m]=s; Qs[m]=q; Dm[m]=d; }
  }
  if (w==0){
    float s=0.f,q=0.f,d=-1e30f;
    if (l < 8){
      int g = chunk*2048 + 2048 + l*4;
      if (g+3 < SEQ){
        float4 A = *(const float4*)(xr + 2048 + l*4);
        float4 P = make_float4(0.f,0.f,0.f,0.f);
        if (g+35 < SEQ) P = *(const float4*)(xr + 2048 + 32 + l*4);
        s = (A.x+A.y)+(A.z+A.w);
        q = fmaf(A.x,A.x, fmaf(A.y,A.y, fmaf(A.z,A.z, A.w*A.w)));
        d = fmaxf(fmaxf(P.x-A.x, P.y-A.y), fmaxf(P.z-A.z, P.w-A.w));
      }
    }
    #pragma unroll
    for (int o=1;o<8;o<<=1){
      s += __shfl_xor(s,o,64);
      q += __shfl_xor(q,o,64);
      d  = fmaxf(d, __shfl_xor(d,o,64));
    }
    if (l==0){ Ss[64]=s; Qs[64]=q; Dm[64]=d; }
  }
  __syncthreads();
  if (threadIdx.x < 64){
    int j = threadIdx.x;
    int p = chunk*64 + j;                 // 0..2047
    if (p < NP){
      float S = Ss[j]+Ss[j+1];
      float Q = Qs[j]+Qs[j+1];
      float mean = S*(1.0f/64.0f);
      float var  = (Q - S*mean)*(1.0f/63.0f);   // ddof=1
      x3[(b*3+0)*NP + p] = mean;
      x3[(b*3+1)*NP + p] = sqrtf(fmaxf(var,0.0f));
      x3[(b*3+2)*NP + p] = c1b[p];              // bias init (gemm atomically adds on top)
    }
    dmaxB[(size_t)b*KPAD + p] = (p < NPM) ? f2bf(fmaxf(Dm[j], Dm[j+1])) : (short)0;
  }
}

// ---------------- K_wB: conv1_w [NP][NPM] fp32 -> Wb [NP][KPAD] bf16 (zero-padded) ----------------
__global__ __launch_bounds__(256) void k_wB(const float* __restrict__ W, float* __restrict__ ws){
  short* Wb = (short*)(ws + OFF_WB);
  int o = blockIdx.y;
  int k = blockIdx.x*256 + threadIdx.x;
  Wb[(size_t)o*KPAD + k] = (k < NPM) ? f2bf(W[(size_t)o*NPM + k]) : (short)0;
}

// ---------------- K_wt: pack conv2 weights fp32 [(i*3+tap)][c]; conv3 weights bf16 [tap][c][i] ----------------
__global__ __launch_bounds__(256) void k_wt(const float* __restrict__ w2, const float* __restrict__ w3, float* __restrict__ ws){
  float* w2c = ws + OFF_W2C;
  short* w3b = (short*)(ws + OFF_W3B);
  int t = blockIdx.x*256 + threadIdx.x;
  if (t < C1*3*C2){
    int r = t / C2, c = t - r*C2;          // r = i*3+tap
    int i = r/3, tap = r - i*3;
    w2c[t] = w2[(c*C1+i)*3 + tap];
  }
  if (t < 3*C3*C2){
    int tap = t / (C3*C2);
    int r = t - tap*(C3*C2);
    int c = r / C2, i = r - c*C2;
    w3b[(tap*C3 + c)*C2 + i] = f2bf(w3[(c*C2+i)*3 + tap]);
  }
}

// ---------------- K2: d2[b,o] += sum_k dmax[b,k]*W[o,k] via MFMA bf16 ----------------
// A = dmaxB [b][k] (m=lane&15 -> b), B = Wb [o][k] (n=lane&15 -> o), fp32 accum.
// Per wave: 1 m-tile x 2 n-tiles; grid (64 n-pairs, 4 m-groups, 4 K-splits); no LDS/SMEM.
__global__ __launch_bounds__(256) void k_gemm(float* __restrict__ ws){
  const short* Ab = (const short*)(ws + OFF_DMAX); // [NB][KPAD]
  const short* Bb = (const short*)(ws + OFF_WB);   // [NP][KPAD]
  float* x3 = ws + OFF_X3;
  int wid  = __builtin_amdgcn_readfirstlane(threadIdx.x >> 6);
  int lane = threadIdx.x & 63;
  int ln = lane & 15, kq = lane >> 4;
  int n0  = blockIdx.x*32;                 // o tile pair base
  int m16 = (blockIdx.y*4 + wid)*16;       // b tile base (wave-uniform)
  int ks  = blockIdx.z*512;                // K split (16 steps of 32)
  f32x4 acc0 = {0.f,0.f,0.f,0.f}, acc1 = {0.f,0.f,0.f,0.f};
  int o0 = n0 + ln, o1 = n0 + 16 + ln;
  const short* ap  = Ab + (size_t)(m16 + ln)*KPAD + ks + kq*8;
  const short* bp0 = Bb + (size_t)min(o0, NP-1)*KPAD + ks + kq*8;
  const short* bp1 = Bb + (size_t)min(o1, NP-1)*KPAD + ks + kq*8;
  #pragma unroll 4
  for (int s=0; s<16; s++){
    short8 av = *(const short8*)(ap  + s*32);
    short8 b0 = *(const short8*)(bp0 + s*32);
    short8 b1 = *(const short8*)(bp1 + s*32);
    acc0 = __builtin_amdgcn_mfma_f32_16x16x32_bf16(av, b0, acc0, 0, 0, 0);
    acc1 = __builtin_amdgcn_mfma_f32_16x16x32_bf16(av, b1, acc1, 0, 0, 0);
  }
  // D[row=kq*4+r][col=ln]: row -> b offset, col -> o offset
  #pragma unroll
  for (int r=0;r<4;r++){
    int b = m16 + kq*4 + r;
    float* xp = x3 + ((size_t)b*3 + 2)*NP;
    if (o0 < NP) atomicAdd(xp + o0, acc0[r]);
    if (o1 < NP) atomicAdd(xp + o1, acc1[r]);
  }
}

// ---------------- K3: conv1 (3->32, k=5, pad=2), plain ----------------
__global__ __launch_bounds__(256) void k_conv1(const float* __restrict__ w1, const float* __restrict__ b1, float* __restrict__ ws){
  const float* x3 = ws + OFF_X3;
  float* y1 = ws + OFF_Y1;
  int b = blockIdx.y;
  int l = blockIdx.x*256 + threadIdx.x;
  bool valid = (l < LEN1);
  float xin[3][5];
  #pragma unroll
  for (int i=0;i<3;i++){
    #pragma unroll
    for (int j=0;j<5;j++){
      int t = l + j - 2;
      xin[i][j] = (valid && t >= 0 && t < LEN1) ? x3[(b*3+i)*NP + t] : 0.f;
    }
  }
  #pragma unroll 8
  for (int c=0;c<C1;c++){
    float a = b1[c];
    #pragma unroll
    for (int i=0;i<3;i++){
      #pragma unroll
      for (int j=0;j<5;j++) a = fmaf(w1[(c*3+i)*5+j], xin[i][j], a);
    }
    if (valid) y1[(b*C1+c)*LEN1 + l] = a;
  }
}

// ---------------- stats (layer1): per-(b,c) sum/sumsq over y1 ----------------
__global__ __launch_bounds__(256) void k_stats(const float* __restrict__ y, float* __restrict__ ps,
                                               float* __restrict__ pq, int C, int L, int npart){
  int b = blockIdx.x, c = blockIdx.y;
  const float* p = y + ((size_t)b*C + c)*L;
  float s=0.f, q=0.f;
  for (int i=threadIdx.x; i<L; i+=256){ float v=p[i]; s+=v; q=fmaf(v,v,q); }
  __shared__ float rs[4], rq[4];
  RED6(s) RED6(q)
  int wid = threadIdx.x>>6, lane = threadIdx.x&63;
  if (lane==0){ rs[wid]=s; rq[wid]=q; }
  __syncthreads();
  if (threadIdx.x==0){
    ps[c*npart + b] = rs[0]+rs[1]+rs[2]+rs[3];
    pq[c*npart + b] = rq[0]+rq[1]+rq[2]+rq[3];
  }
}

// ---------------- finalize BN from partials ----------------
__global__ __launch_bounds__(256) void k_fin(const float* __restrict__ ps, const float* __restrict__ pq,
                                             const float* __restrict__ g, const float* __restrict__ be,
                                             float* __restrict__ stats, int C, int npart, double invN){
  int c = blockIdx.x;
  double s=0.0, q=0.0;
  for (int j=threadIdx.x; j<npart; j+=256){ s += (double)ps[c*npart+j]; q += (double)pq[c*npart+j]; }
  #pragma unroll
  for (int off=32; off; off>>=1){ s += __shfl_xor(s,off,64); q += __shfl_xor(q,off,64); }
  __shared__ double rs[4], rq[4];
  int wid = threadIdx.x>>6, lane=threadIdx.x&63;
  if (lane==0){ rs[wid]=s; rq[wid]=q; }
  __syncthreads();
  if (threadIdx.x==0){
    double S = rs[0]+rs[1]+rs[2]+rs[3];
    double Q = rq[0]+rq[1]+rq[2]+rq[3];
    double mean = S*invN;
    double var  = Q*invN - mean*mean;
    double a = (double)g[c] / sqrt(var + 1e-5);
    stats[c]   = (float)a;
    stats[C+c] = (float)((double)be[c] - mean*a);
  }
}

// ---------------- K4: pool1 — h1[b][i][m] = relu(bn1(max(y1[2m], y1[2m+1]))) ----------------
__global__ __launch_bounds__(256) void k_pool1(float* __restrict__ ws){
  const float* y1 = ws + OFF_Y1;
  const float* st = ws + OFF_S1;
  float* h1 = ws + OFF_H1;
  int b = blockIdx.z, i = blockIdx.y;
  int m = blockIdx.x*256 + threadIdx.x;
  if (m < LEN2){
    float sa = st[i], sb = st[C1+i];
    const float* yr = y1 + ((size_t)b*C1 + i)*LEN1 + 2*m;
    float v = fmaxf(yr[0], yr[1]);
    h1[((size_t)b*C1 + i)*LEN2 + m] = fmaxf(fmaf(sa, v, sb), 0.f);
  }
}

// ---------------- K5: conv2 (32->64) — lanes=channel; h via SMEM (grouped x2); weights via VMEM ----------------
__global__ __launch_bounds__(256) void k_conv2(const float* __restrict__ b2, float* __restrict__ ws){
  const float* h1  = ws + OFF_H1;     // [b][i][m], m<LEN2
  const float* w2c = ws + OFF_W2C;    // [(i*3+tap)][c]
  float* pmaxT = ws + OFF_PMAX;       // [b][m][c], m<LEN3
  float* ps = ws + OFF_PS;
  float* pq = ws + OFF_PQ;
  int b = blockIdx.y;
  int blk = blockIdx.x;               // 0..7 (128 positions each)
  int w  = __builtin_amdgcn_readfirstlane(threadIdx.x >> 6);
  int lane = threadIdx.x & 63;
  int p0 = blk*128 + w*32;            // wave-uniform
  int c  = lane;
#define AD2(p) float acc##p = b2[c];
  ACCS32(AD2)
  const float* hb = h1 + (size_t)b*C1*LEN2 + p0 - 1;
  const float* wb = w2c + c;
  #pragma unroll 1
  for (int i=0;i<C1;i+=2){
    const float* hpA = hb + (size_t)i*LEN2;      // wave-uniform -> s_load
    const float* hpB = hpA + LEN2;
    HS34(HLA)
    HS34(HLB)
    if (p0 == 0){ hh0 = 0.f; gg0 = 0.f; }
    if (p0 == 992){ hh32 = 0.f; hh33 = 0.f; gg32 = 0.f; gg33 = 0.f; }
    const float* wvA = wb + (i*3)*C2;            // per-lane coalesced VMEM
    const float* wvB = wb + ((i+1)*3)*C2;
    float w0a_ = wvA[0], w1a_ = wvA[C2], w2a_ = wvA[2*C2];
    float w0b_ = wvB[0], w1b_ = wvB[C2], w2b_ = wvB[2*C2];
    CONVSTEPS(CFA)
    CONVSTEPS(CFB)
  }
  int m0 = p0 >> 1;
  float* pp = pmaxT + ((size_t)b*LEN3 + m0)*C2 + c;
#define PST2(j,e,o) if (m0 + j < LEN3) pp[(size_t)(j)*C2] = fmaxf(acc##e, acc##o);
  POOL16(PST2)
  float ss = 0.f, qq = 0.f;
#define SAC2(p) if (p0 + p < LEN2){ ss += acc##p; qq = fmaf(acc##p, acc##p, qq); }
  ACCS32(SAC2)
  __shared__ float es[4][64], eq[4][64];
  es[w][lane] = ss; eq[w][lane] = qq;
  __syncthreads();
  if (w == 0){
    int pidx = b*8 + blk;
    float S = es[0][lane]+es[1][lane]+es[2][lane]+es[3][lane];
    float Q = eq[0][lane]+eq[1][lane]+eq[2][lane]+eq[3][lane];
    ps[lane*NPART + pidx] = S;
    pq[lane*NPART + pidx] = Q;
  }
}

// ---------------- K6: p2bf — h2T[b][m+1][c] = bf16(relu(bn2(pmaxT[b][m][c]))); zero pad rows ----------------
__global__ __launch_bounds__(256) void k_p2bf(float* __restrict__ ws){
  const float* pm = ws + OFF_PMAX;   // [b][m][c]
  const float* st = ws + OFF_S2;
  short* h2t = (short*)(ws + OFF_H2T); // [b][LPAD][C2], row r = position r-1
  int b = blockIdx.y;
  int idx = blockIdx.x*256 + threadIdx.x;
  if (idx < LEN3*C2){
    int m = idx >> 6, c = idx & 63;
    float v = fmaxf(fmaf(st[c], pm[((size_t)b*LEN3 + m)*C2 + c], st[C2+c]), 0.f);
    h2t[((size_t)b*LPAD + m + 1)*C2 + c] = f2bf(v);
  } else {
    int zr = idx - LEN3*C2;          // 192 pad slots: rows 0, 512, 513
    if (zr < 3*C2){
      int rsel = zr >> 6, c = zr & 63;
      int row = (rsel == 0) ? 0 : (511 + rsel);   // 0, 512, 513
      h2t[((size_t)b*LPAD + row)*C2 + c] = 0;
    }
  }
}

// ---------------- K7: conv3 via MFMA bf16 — y3[c][l] = sum_tap W_tap · h2[.][l+tap-1] ----------------
__global__ __launch_bounds__(256) void k_conv3m(const float* __restrict__ b3, float* __restrict__ ws){
  const short* h2t = (const short*)(ws + OFF_H2T);  // [b][LPAD][C2]
  const short* w3b = (const short*)(ws + OFF_W3B);  // [tap][C3][C2]
  float* y3t = ws + OFF_Y3T;                        // [b][l][c]
  int b  = blockIdx.z;
  int cg = blockIdx.y;                 // 0/1: 64-channel half
  int wid = __builtin_amdgcn_readfirstlane(threadIdx.x >> 6);
  int lane = threadIdx.x & 63;
  int lt = blockIdx.x*4 + wid;         // 0..31
  int ln = lane & 15, kq = lane >> 4;
  int l  = lt*16 + ln;                 // output position (col); l==511 discarded
  int cb = cg*64;
  f32x4 acc0 = *(const f32x4*)(b3 + cb +  0 + kq*4);   // bias in C-frag (broadcast over n)
  f32x4 acc1 = *(const f32x4*)(b3 + cb + 16 + kq*4);
  f32x4 acc2 = *(const f32x4*)(b3 + cb + 32 + kq*4);
  f32x4 acc3 = *(const f32x4*)(b3 + cb + 48 + kq*4);
  const short* hB = h2t + ((size_t)b*LPAD + l)*C2 + kq*8;          // + tap*C2 + s*32
  const short* wA = w3b + ((size_t)(cb + ln))*C2 + kq*8;           // + tap*C3*C2 + ct*16*C2 + s*32
  #pragma unroll
  for (int t=0;t<3;t++){
    #pragma unroll
    for (int s=0;s<2;s++){
      short8 bv = *(const short8*)(hB + t*C2 + s*32);
      short8 a0 = *(const short8*)(wA + t*C3*C2 +    0 + s*32);
      short8 a1 = *(const short8*)(wA + t*C3*C2 + 1024 + s*32);
      short8 a2 = *(const short8*)(wA + t*C3*C2 + 2048 + s*32);
      short8 a3 = *(const short8*)(wA + t*C3*C2 + 3072 + s*32);
      acc0 = __builtin_amdgcn_mfma_f32_16x16x32_bf16(a0, bv, acc0, 0, 0, 0);
      acc1 = __builtin_amdgcn_mfma_f32_16x16x32_bf16(a1, bv, acc1, 0, 0, 0);
      acc2 = __builtin_amdgcn_mfma_f32_16x16x32_bf16(a2, bv, acc2, 0, 0, 0);
      acc3 = __builtin_amdgcn_mfma_f32_16x16x32_bf16(a3, bv, acc3, 0, 0, 0);
    }
  }
  if (l < LEN3){
    float* yp = y3t + ((size_t)b*LEN3 + l)*C3 + cb + kq*4;
    *(f32x4*)(yp +  0) = acc0;
    *(f32x4*)(yp + 16) = acc1;
    *(f32x4*)(yp + 32) = acc2;
    *(f32x4*)(yp + 48) = acc3;
  }
}

// ---------------- K8: stats3 — per-channel sum/sumsq over y3t [b][l][c] ----------------
__global__ __launch_bounds__(1024) void k_stats3(float* __restrict__ ws){
  const float* y3t = ws + OFF_Y3T;
  float* ps = ws + OFF_PS;
  float* pq = ws + OFF_PQ;
  int b = blockIdx.x;
  int tid = threadIdx.x;
  int c = tid & 127, ph = tid >> 7;    // 8 phases
  const float* yb = y3t + (size_t)b*LEN3*C3 + c;
  float s = 0.f, q = 0.f;
  for (int l=ph; l<LEN3; l+=8){ float v = yb[(size_t)l*C3]; s += v; q = fmaf(v,v,q); }
  __shared__ float rs[1024], rq[1024];
  rs[tid] = s; rq[tid] = q;
  __syncthreads();
  if (tid < 128){
    float S = 0.f, Q = 0.f;
    #pragma unroll
    for (int k=0;k<8;k++){ S += rs[k*128 + tid]; Q += rq[k*128 + tid]; }
    ps[tid*NB + b] = S;
    pq[tid*NB + b] = Q;
  }
}

// ---------------- K9: bn3+relu+mean over y3t [b][l][c] ----------------
__global__ __launch_bounds__(1024) void k_out(float* __restrict__ out, const float* __restrict__ ws){
  const float* y3t = ws + OFF_Y3T;
  const float* st = ws + OFF_S3;
  int b = blockIdx.x;
  int tid = threadIdx.x;
  int c = tid & 127, ph = tid >> 7;     // 8 phases
  float a = st[c], sh = st[C3+c];
  const float* yb = y3t + (size_t)b*LEN3*C3 + c;
  float s = 0.f;
  for (int l=ph; l<LEN3; l+=8) s += fmaxf(fmaf(a, yb[(size_t)l*C3], sh), 0.f);
  __shared__ float red[1024];
  red[tid] = s;
  __syncthreads();
  if (tid < 128){
    float t = 0.f;
    #pragma unroll
    for (int k=0;k<8;k++) t += red[k*128 + tid];
    out[b*C3 + tid] = t * (1.0f/511.0f);
  }
}

extern "C" void kernel_launch(void* const* d_in, const int* in_sizes, int n_in,
                              void* d_out, int out_size, void* d_ws, size_t ws_size,
                              hipStream_t stream) {
  const float* x   = (const float*)d_in[0];
  const float* c1w = (const float*)d_in[1];
  const float* c1b = (const float*)d_in[2];
  const float* w1  = (const float*)d_in[3];
  const float* b1  = (const float*)d_in[4];
  const float* g1  = (const float*)d_in[5];
  const float* be1 = (const float*)d_in[6];
  const float* w2  = (const float*)d_in[7];
  const float* b2  = (const float*)d_in[8];
  const float* g2  = (const float*)d_in[9];
  const float* be2 = (const float*)d_in[10];
  const float* w3  = (const float*)d_in[11];
  const float* b3  = (const float*)d_in[12];
  const float* g3  = (const float*)d_in[13];
  const float* be3 = (const float*)d_in[14];
  float* ws  = (float*)d_ws;
  float* out = (float*)d_out;

  hipLaunchKernelGGL(k_patch,  dim3(32,NB), dim3(256), 0, stream, x, c1b, ws);
  hipLaunchKernelGGL(k_wB,     dim3(KPAD/256, NP), dim3(256), 0, stream, c1w, ws);
  hipLaunchKernelGGL(k_wt,     dim3((3*C3*C2+255)/256), dim3(256), 0, stream, w2, w3, ws);
  hipLaunchKernelGGL(k_gemm,   dim3(64,4,4), dim3(256), 0, stream, ws);
  hipLaunchKernelGGL(k_conv1,  dim3(8,NB), dim3(256), 0, stream, w1, b1, ws);
  hipLaunchKernelGGL(k_stats,  dim3(NB,C1), dim3(256), 0, stream, ws+OFF_Y1, ws+OFF_PS, ws+OFF_PQ, C1, LEN1, NB);
  hipLaunchKernelGGL(k_fin,    dim3(C1), dim3(256), 0, stream, ws+OFF_PS, ws+OFF_PQ, g1, be1, ws+OFF_S1, C1, NB, 1.0/((double)NB*LEN1));
  hipLaunchKernelGGL(k_pool1,  dim3(4,C1,NB), dim3(256), 0, stream, ws);
  hipLaunchKernelGGL(k_conv2,  dim3(8,NB), dim3(256), 0, stream, b2, ws);
  hipLaunchKernelGGL(k_fin,    dim3(C2), dim3(256), 0, stream, ws+OFF_PS, ws+OFF_PQ, g2, be2, ws+OFF_S2, C2, NPART, 1.0/((double)NB*LEN2));
  hipLaunchKernelGGL(k_p2bf,   dim3((LEN3*C2+3*C2+255)/256, NB), dim3(256), 0, stream, ws);
  hipLaunchKernelGGL(k_conv3m, dim3(8,2,NB), dim3(256), 0, stream, b3, ws);
  hipLaunchKernelGGL(k_stats3, dim3(NB), dim3(1024), 0, stream, ws);
  hipLaunchKernelGGL(k_fin,    dim3(C3), dim3(256), 0, stream, ws+OFF_PS, ws+OFF_PQ, g3, be3, ws+OFF_S3, C3, NB, 1.0/((double)NB*LEN3));
  hipLaunchKernelGGL(k_out,    dim3(NB), dim3(1024), 0, stream, out, ws);
}

// Round 16
// 353.370 us; speedup vs baseline: 1.4238x; 1.1326x over previous
//
#include <hip/hip_runtime.h>
#include <math.h>

#define NB 256
#define SEQ 65536
#define NP 2047
#define NPM 2046
#define KPAD 2048  // gemm K padded (bf16 operands zero-filled at k=2046,2047)
#define LEN1 2047
#define LEN2 1023
#define LEN3 511
#define C1 32
#define C2 64
#define C3 128
#define NPART 2048
#define LPAD 514   // h2T rows: pos -1 .. 512 (zero-padded ends)

// workspace offsets (floats). Region timeline:
//   Y2: gemm Wb (bf16) -> h1 (pool1 out) -> h2T (bf16, p2bf out)
//   Y1: y1 (conv1 out) -> pmaxT (conv2 out) -> y3t (conv3m out, [b][c][l])
//   DMAX: dmax bf16 [b][KPAD]
#define OFF_X3   0
#define SZ_X3    (NB*3*NP)
#define OFF_DMAX (OFF_X3 + SZ_X3)
#define SZ_DMAX  (NB*NPM)
#define OFF_Y1   (OFF_DMAX + SZ_DMAX)
#define SZ_Y1    (NB*C1*LEN1)
#define OFF_Y2   (OFF_Y1 + SZ_Y1)
#define SZ_Y2    (NB*C2*LEN2)
#define OFF_S1   (OFF_Y2 + SZ_Y2)
#define OFF_S2   (OFF_S1 + 2*C1)
#define OFF_S3   (OFF_S2 + 2*C2)
#define OFF_W2C  (OFF_S3 + 2*C3)
#define OFF_W3B  (OFF_W2C + C1*C2*3)   // conv3 weights bf16 [tap][c][i]
#define OFF_PS   (OFF_W3B + C2*C3*3)
#define OFF_PQ   (OFF_PS + C3*NPART)
#define OFF_WB   OFF_Y2   // gemm W bf16 [NP][KPAD] (dead after gemm)
#define OFF_H1   OFF_Y2   // pooled bn1 activations [b][i][m], m<LEN2
#define OFF_H2T  OFF_Y2   // bf16 [b][LPAD][C2] (h1 dead after conv2)
#define OFF_PMAX OFF_Y1   // conv2 pooled-raw out [b][m][c], m<LEN3
#define OFF_Y3T  OFF_Y1   // y3 [b][c][l] (pmaxT dead after p2bf)

typedef __attribute__((ext_vector_type(8))) short short8;
typedef __attribute__((ext_vector_type(4))) float f32x4;

__device__ inline short f2bf(float f){
  union { float f; unsigned u; } x; x.f = f;
  unsigned r = x.u + 0x7FFF + ((x.u >> 16) & 1);   // RNE; inputs are normal finite
  return (short)(r >> 16);
}

#define ACCS16(X) X(0) X(1) X(2) X(3) X(4) X(5) X(6) X(7) \
                  X(8) X(9) X(10) X(11) X(12) X(13) X(14) X(15)
#define ACCS32(X) ACCS16(X) X(16) X(17) X(18) X(19) X(20) X(21) X(22) X(23) \
                  X(24) X(25) X(26) X(27) X(28) X(29) X(30) X(31)
#define HS34(X) X(0) X(1) X(2) X(3) X(4) X(5) X(6) X(7) X(8) X(9) X(10) X(11) \
                X(12) X(13) X(14) X(15) X(16) X(17) X(18) X(19) X(20) X(21) \
                X(22) X(23) X(24) X(25) X(26) X(27) X(28) X(29) X(30) X(31) X(32) X(33)
#define POOL16(X) X(0,0,1) X(1,2,3) X(2,4,5) X(3,6,7) X(4,8,9) X(5,10,11) X(6,12,13) X(7,14,15) \
                  X(8,16,17) X(9,18,19) X(10,20,21) X(11,22,23) X(12,24,25) X(13,26,27) X(14,28,29) X(15,30,31)

#define RED6(v) v += __shfl_xor(v,32,64); v += __shfl_xor(v,16,64); \
                v += __shfl_xor(v, 8,64); v += __shfl_xor(v, 4,64); \
                v += __shfl_xor(v, 2,64); v += __shfl_xor(v, 1,64);
#define RED4L(v) v += __shfl_xor(v,1,64); v += __shfl_xor(v,2,64); \
                 v += __shfl_xor(v,4,64); v += __shfl_xor(v,8,64);

// fp32 conv2 K-loop macros (R13 form — SMEM grouped x2)
#define HLA(j) float hh##j = hpA[j];
#define HLB(j) float gg##j = hpB[j];
#define CFA(p,j0,j1,j2) acc##p = fmaf(w0a_, hh##j0, acc##p); \
                        acc##p = fmaf(w1a_, hh##j1, acc##p); \
                        acc##p = fmaf(w2a_, hh##j2, acc##p);
#define CFB(p,j0,j1,j2) acc##p = fmaf(w0b_, gg##j0, acc##p); \
                        acc##p = fmaf(w1b_, gg##j1, acc##p); \
                        acc##p = fmaf(w2b_, gg##j2, acc##p);
#define CONVSTEPS(CF_) CF_(0,0,1,2)    CF_(1,1,2,3)    CF_(2,2,3,4)    CF_(3,3,4,5) \
              CF_(4,4,5,6)    CF_(5,5,6,7)    CF_(6,6,7,8)    CF_(7,7,8,9) \
              CF_(8,8,9,10)   CF_(9,9,10,11)  CF_(10,10,11,12) CF_(11,11,12,13) \
              CF_(12,12,13,14) CF_(13,13,14,15) CF_(14,14,15,16) CF_(15,15,16,17) \
              CF_(16,16,17,18) CF_(17,17,18,19) CF_(18,18,19,20) CF_(19,19,20,21) \
              CF_(20,20,21,22) CF_(21,21,22,23) CF_(22,22,23,24) CF_(23,23,24,25) \
              CF_(24,24,25,26) CF_(25,25,26,27) CF_(26,26,27,28) CF_(27,27,28,29) \
              CF_(28,28,29,30) CF_(29,29,30,31) CF_(30,30,31,32) CF_(31,31,32,33)

// MFMA conv3 tile grid: (lt, ct) in 4x4
#define TILES(X) X(0,0) X(0,1) X(0,2) X(0,3) X(1,0) X(1,1) X(1,2) X(1,3) \
                 X(2,0) X(2,1) X(2,2) X(2,3) X(3,0) X(3,1) X(3,2) X(3,3)

// ---------------- K1: patch mean/std + dmax (bf16, [b][KPAD]) + x3-ch2 bias init ----------------
__global__ __launch_bounds__(256) void k_patch(const float* __restrict__ x, const float* __restrict__ c1b,
                                               float* __restrict__ ws){
  float* x3    = ws + OFF_X3;
  short* dmaxB = (short*)(ws + OFF_DMAX);   // bf16 [NB][KPAD], zero-padded k>=NPM
  int b = blockIdx.y;
  int chunk = blockIdx.x;              // 0..31, 2048 floats each
  const float* xr = x + (size_t)b*SEQ + chunk*2048;
  __shared__ float Ss[65], Qs[65], Dm[65];
  int w = threadIdx.x >> 6;
  int l = threadIdx.x & 63;
  #pragma unroll
  for (int i=0;i<2;i++){
    int seg = w*2 + i;
    int off = seg*256;
    float4 A = *(const float4*)(xr + off + l*4);
    float4 Bh = make_float4(0.f,0.f,0.f,0.f);
    if (l >= 56){
      int g = chunk*2048 + off + 256 + (l-56)*4;
      if (g + 3 < SEQ) Bh = *(const float4*)(xr + off + 256 + (l-56)*4);
    }
    int src = (l+8) & 63;
    float p0 = __shfl(A.x, src, 64), p1 = __shfl(A.y, src, 64),
          p2 = __shfl(A.z, src, 64), p3 = __shfl(A.w, src, 64);
    if (l >= 56){ p0=Bh.x; p1=Bh.y; p2=Bh.z; p3=Bh.w; }
    float s = (A.x+A.y)+(A.z+A.w);
    float q = fmaf(A.x,A.x, fmaf(A.y,A.y, fmaf(A.z,A.z, A.w*A.w)));
    float d = fmaxf(fmaxf(p0-A.x, p1-A.y), fmaxf(p2-A.z, p3-A.w));
    #pragma unroll
    for (int o=1;o<8;o<<=1){
      s += __shfl_xor(s,o,64);
      q += __shfl_xor(q,o,64);
      d  = fmaxf(d, __shfl_xor(d,o,64));
    }
    if ((l&7)==0){ int m = seg*8 + (l>>3); Ss[m]=s; Qs[m]=q; Dm[m]=d; }
  }
  if (w==0){
    float s=0.f,q=0.f,d=-1e30f;
    if (l < 8){
      int g = chunk*2048 + 2048 + l*4;
      if (g+3 < SEQ){
        float4 A = *(const float4*)(xr + 2048 + l*4);
        float4 P = make_float4(0.f,0.f,0.f,0.f);
        if (g+35 < SEQ) P = *(const float4*)(xr + 2048 + 32 + l*4);
        s = (A.x+A.y)+(A.z+A.w);
        q = fmaf(A.x,A.x, fmaf(A.y,A.y, fmaf(A.z,A.z, A.w*A.w)));
        d = fmaxf(fmaxf(P.x-A.x, P.y-A.y), fmaxf(P.z-A.z, P.w-A.w));
      }
    }
    #pragma unroll
    for (int o=1;o<8;o<<=1){
      s += __shfl_xor(s,o,64);
      q += __shfl_xor(q,o,64);
      d  = fmaxf(d, __shfl_xor(d,o,64));
    }
    if (l==0){ Ss[64]=s; Qs[64]=q; Dm[64]=d; }
  }
  __syncthreads();
  if (threadIdx.x < 64){
    int j = threadIdx.x;
    int p = chunk*64 + j;                 // 0..2047
    if (p < NP){
      float S = Ss[j]+Ss[j+1];
      float Q = Qs[j]+Qs[j+1];
      float mean = S*(1.0f/64.0f);
      float var  = (Q - S*mean)*(1.0f/63.0f);   // ddof=1
      x3[(b*3+0)*NP + p] = mean;
      x3[(b*3+1)*NP + p] = sqrtf(fmaxf(var,0.0f));
      x3[(b*3+2)*NP + p] = c1b[p];              // bias init (gemm atomically adds on top)
    }
    dmaxB[(size_t)b*KPAD + p] = (p < NPM) ? f2bf(fmaxf(Dm[j], Dm[j+1])) : (short)0;
  }
}

// ---------------- K_wB: conv1_w [NP][NPM] fp32 -> Wb [NP][KPAD] bf16 (zero-padded) ----------------
__global__ __launch_bounds__(256) void k_wB(const float* __restrict__ W, float* __restrict__ ws){
  short* Wb = (short*)(ws + OFF_WB);
  int o = blockIdx.y;
  int k = blockIdx.x*256 + threadIdx.x;
  Wb[(size_t)o*KPAD + k] = (k < NPM) ? f2bf(W[(size_t)o*NPM + k]) : (short)0;
}

// ---------------- K_wt: pack conv2 weights fp32 [(i*3+tap)][c]; conv3 weights bf16 [tap][c][i] ----------------
__global__ __launch_bounds__(256) void k_wt(const float* __restrict__ w2, const float* __restrict__ w3, float* __restrict__ ws){
  float* w2c = ws + OFF_W2C;
  short* w3b = (short*)(ws + OFF_W3B);
  int t = blockIdx.x*256 + threadIdx.x;
  if (t < C1*3*C2){
    int r = t / C2, c = t - r*C2;          // r = i*3+tap
    int i = r/3, tap = r - i*3;
    w2c[t] = w2[(c*C1+i)*3 + tap];
  }
  if (t < 3*C3*C2){
    int tap = t / (C3*C2);
    int r = t - tap*(C3*C2);
    int c = r / C2, i = r - c*C2;
    w3b[(tap*C3 + c)*C2 + i] = f2bf(w3[(c*C2+i)*3 + tap]);
  }
}

// ---------------- K2: d2[b,o] += sum_k dmax[b,k]*W[o,k] via MFMA bf16 ----------------
__global__ __launch_bounds__(256) void k_gemm(float* __restrict__ ws){
  const short* Ab = (const short*)(ws + OFF_DMAX); // [NB][KPAD]
  const short* Bb = (const short*)(ws + OFF_WB);   // [NP][KPAD]
  float* x3 = ws + OFF_X3;
  int wid  = __builtin_amdgcn_readfirstlane(threadIdx.x >> 6);
  int lane = threadIdx.x & 63;
  int ln = lane & 15, kq = lane >> 4;
  int n0  = blockIdx.x*32;                 // o tile pair base
  int m16 = (blockIdx.y*4 + wid)*16;       // b tile base (wave-uniform)
  int ks  = blockIdx.z*512;                // K split (16 steps of 32)
  f32x4 acc0 = {0.f,0.f,0.f,0.f}, acc1 = {0.f,0.f,0.f,0.f};
  int o0 = n0 + ln, o1 = n0 + 16 + ln;
  const short* ap  = Ab + (size_t)(m16 + ln)*KPAD + ks + kq*8;
  const short* bp0 = Bb + (size_t)min(o0, NP-1)*KPAD + ks + kq*8;
  const short* bp1 = Bb + (size_t)min(o1, NP-1)*KPAD + ks + kq*8;
  #pragma unroll 4
  for (int s=0; s<16; s++){
    short8 av = *(const short8*)(ap  + s*32);
    short8 b0 = *(const short8*)(bp0 + s*32);
    short8 b1 = *(const short8*)(bp1 + s*32);
    acc0 = __builtin_amdgcn_mfma_f32_16x16x32_bf16(av, b0, acc0, 0, 0, 0);
    acc1 = __builtin_amdgcn_mfma_f32_16x16x32_bf16(av, b1, acc1, 0, 0, 0);
  }
  // D[row=kq*4+r][col=ln]: row -> b offset, col -> o offset
  #pragma unroll
  for (int r=0;r<4;r++){
    int b = m16 + kq*4 + r;
    float* xp = x3 + ((size_t)b*3 + 2)*NP;
    if (o0 < NP) atomicAdd(xp + o0, acc0[r]);
    if (o1 < NP) atomicAdd(xp + o1, acc1[r]);
  }
}

// ---------------- K3: conv1 (3->32, k=5, pad=2), plain ----------------
__global__ __launch_bounds__(256) void k_conv1(const float* __restrict__ w1, const float* __restrict__ b1, float* __restrict__ ws){
  const float* x3 = ws + OFF_X3;
  float* y1 = ws + OFF_Y1;
  int b = blockIdx.y;
  int l = blockIdx.x*256 + threadIdx.x;
  bool valid = (l < LEN1);
  float xin[3][5];
  #pragma unroll
  for (int i=0;i<3;i++){
    #pragma unroll
    for (int j=0;j<5;j++){
      int t = l + j - 2;
      xin[i][j] = (valid && t >= 0 && t < LEN1) ? x3[(b*3+i)*NP + t] : 0.f;
    }
  }
  #pragma unroll 8
  for (int c=0;c<C1;c++){
    float a = b1[c];
    #pragma unroll
    for (int i=0;i<3;i++){
      #pragma unroll
      for (int j=0;j<5;j++) a = fmaf(w1[(c*3+i)*5+j], xin[i][j], a);
    }
    if (valid) y1[(b*C1+c)*LEN1 + l] = a;
  }
}

// ---------------- stats (layer1): per-(b,c) sum/sumsq over y1 ----------------
__global__ __launch_bounds__(256) void k_stats(const float* __restrict__ y, float* __restrict__ ps,
                                               float* __restrict__ pq, int C, int L, int npart){
  int b = blockIdx.x, c = blockIdx.y;
  const float* p = y + ((size_t)b*C + c)*L;
  float s=0.f, q=0.f;
  for (int i=threadIdx.x; i<L; i+=256){ float v=p[i]; s+=v; q=fmaf(v,v,q); }
  __shared__ float rs[4], rq[4];
  RED6(s) RED6(q)
  int wid = threadIdx.x>>6, lane = threadIdx.x&63;
  if (lane==0){ rs[wid]=s; rq[wid]=q; }
  __syncthreads();
  if (threadIdx.x==0){
    ps[c*npart + b] = rs[0]+rs[1]+rs[2]+rs[3];
    pq[c*npart + b] = rq[0]+rq[1]+rq[2]+rq[3];
  }
}

// ---------------- finalize BN from partials ----------------
__global__ __launch_bounds__(256) void k_fin(const float* __restrict__ ps, const float* __restrict__ pq,
                                             const float* __restrict__ g, const float* __restrict__ be,
                                             float* __restrict__ stats, int C, int npart, double invN){
  int c = blockIdx.x;
  double s=0.0, q=0.0;
  for (int j=threadIdx.x; j<npart; j+=256){ s += (double)ps[c*npart+j]; q += (double)pq[c*npart+j]; }
  #pragma unroll
  for (int off=32; off; off>>=1){ s += __shfl_xor(s,off,64); q += __shfl_xor(q,off,64); }
  __shared__ double rs[4], rq[4];
  int wid = threadIdx.x>>6, lane=threadIdx.x&63;
  if (lane==0){ rs[wid]=s; rq[wid]=q; }
  __syncthreads();
  if (threadIdx.x==0){
    double S = rs[0]+rs[1]+rs[2]+rs[3];
    double Q = rq[0]+rq[1]+rq[2]+rq[3];
    double mean = S*invN;
    double var  = Q*invN - mean*mean;
    double a = (double)g[c] / sqrt(var + 1e-5);
    stats[c]   = (float)a;
    stats[C+c] = (float)((double)be[c] - mean*a);
  }
}

// ---------------- K4: pool1 — h1[b][i][m] = relu(bn1(max(y1[2m], y1[2m+1]))) ----------------
__global__ __launch_bounds__(256) void k_pool1(float* __restrict__ ws){
  const float* y1 = ws + OFF_Y1;
  const float* st = ws + OFF_S1;
  float* h1 = ws + OFF_H1;
  int b = blockIdx.z, i = blockIdx.y;
  int m = blockIdx.x*256 + threadIdx.x;
  if (m < LEN2){
    float sa = st[i], sb = st[C1+i];
    const float* yr = y1 + ((size_t)b*C1 + i)*LEN1 + 2*m;
    float v = fmaxf(yr[0], yr[1]);
    h1[((size_t)b*C1 + i)*LEN2 + m] = fmaxf(fmaf(sa, v, sb), 0.f);
  }
}

// ---------------- K5: conv2 (32->64) — lanes=channel; h via SMEM (grouped x2); weights via VMEM ----------------
__global__ __launch_bounds__(256) void k_conv2(const float* __restrict__ b2, float* __restrict__ ws){
  const float* h1  = ws + OFF_H1;     // [b][i][m], m<LEN2
  const float* w2c = ws + OFF_W2C;    // [(i*3+tap)][c]
  float* pmaxT = ws + OFF_PMAX;       // [b][m][c], m<LEN3
  float* ps = ws + OFF_PS;
  float* pq = ws + OFF_PQ;
  int b = blockIdx.y;
  int blk = blockIdx.x;               // 0..7 (128 positions each)
  int w  = __builtin_amdgcn_readfirstlane(threadIdx.x >> 6);
  int lane = threadIdx.x & 63;
  int p0 = blk*128 + w*32;            // wave-uniform
  int c  = lane;
#define AD2(p) float acc##p = b2[c];
  ACCS32(AD2)
  const float* hb = h1 + (size_t)b*C1*LEN2 + p0 - 1;
  const float* wb = w2c + c;
  #pragma unroll 1
  for (int i=0;i<C1;i+=2){
    const float* hpA = hb + (size_t)i*LEN2;      // wave-uniform -> s_load
    const float* hpB = hpA + LEN2;
    HS34(HLA)
    HS34(HLB)
    if (p0 == 0){ hh0 = 0.f; gg0 = 0.f; }
    if (p0 == 992){ hh32 = 0.f; hh33 = 0.f; gg32 = 0.f; gg33 = 0.f; }
    const float* wvA = wb + (i*3)*C2;            // per-lane coalesced VMEM
    const float* wvB = wb + ((i+1)*3)*C2;
    float w0a_ = wvA[0], w1a_ = wvA[C2], w2a_ = wvA[2*C2];
    float w0b_ = wvB[0], w1b_ = wvB[C2], w2b_ = wvB[2*C2];
    CONVSTEPS(CFA)
    CONVSTEPS(CFB)
  }
  int m0 = p0 >> 1;
  float* pp = pmaxT + ((size_t)b*LEN3 + m0)*C2 + c;
#define PST2(j,e,o) if (m0 + j < LEN3) pp[(size_t)(j)*C2] = fmaxf(acc##e, acc##o);
  POOL16(PST2)
  float ss = 0.f, qq = 0.f;
#define SAC2(p) if (p0 + p < LEN2){ ss += acc##p; qq = fmaf(acc##p, acc##p, qq); }
  ACCS32(SAC2)
  __shared__ float es[4][64], eq[4][64];
  es[w][lane] = ss; eq[w][lane] = qq;
  __syncthreads();
  if (w == 0){
    int pidx = b*8 + blk;
    float S = es[0][lane]+es[1][lane]+es[2][lane]+es[3][lane];
    float Q = eq[0][lane]+eq[1][lane]+eq[2][lane]+eq[3][lane];
    ps[lane*NPART + pidx] = S;
    pq[lane*NPART + pidx] = Q;
  }
}

// ---------------- K6: p2bf — h2T[b][m+1][c] = bf16(relu(bn2(pmaxT[b][m][c]))); zero pad rows ----------------
__global__ __launch_bounds__(256) void k_p2bf(float* __restrict__ ws){
  const float* pm = ws + OFF_PMAX;   // [b][m][c]
  const float* st = ws + OFF_S2;
  short* h2t = (short*)(ws + OFF_H2T); // [b][LPAD][C2], row r = position r-1
  int b = blockIdx.y;
  int idx = blockIdx.x*256 + threadIdx.x;
  if (idx < LEN3*C2){
    int m = idx >> 6, c = idx & 63;
    float v = fmaxf(fmaf(st[c], pm[((size_t)b*LEN3 + m)*C2 + c], st[C2+c]), 0.f);
    h2t[((size_t)b*LPAD + m + 1)*C2 + c] = f2bf(v);
  } else {
    int zr = idx - LEN3*C2;          // 192 pad slots: rows 0, 512, 513
    if (zr < 3*C2){
      int rsel = zr >> 6, c = zr & 63;
      int row = (rsel == 0) ? 0 : (511 + rsel);   // 0, 512, 513
      h2t[((size_t)b*LPAD + row)*C2 + c] = 0;
    }
  }
}

// ---------------- K7: conv3 via MFMA bf16, 4x4 register-blocked + fused BN3 stats ----------------
// Block = 4 waves; wave = 64 l x 64 c (16 named f32x4 accs). Per (t,s) step: 8 frag loads,
// 16 MFMAs (0.5 loads/MFMA vs 1.25 in R15). y3t stored [b][c][l] (coalesced 64B runs).
// Stats: Σ over l in-register + 4-step shfl_xor over ln; lane ln==0 writes partials.
__global__ __launch_bounds__(256) void k_conv3m(const float* __restrict__ b3, float* __restrict__ ws){
  const short* h2t = (const short*)(ws + OFF_H2T);  // [b][LPAD][C2]
  const short* w3b = (const short*)(ws + OFF_W3B);  // [tap][C3][C2]
  float* y3t = ws + OFF_Y3T;                        // [b][c][l]
  float* ps = ws + OFF_PS;
  float* pq = ws + OFF_PQ;
  int b   = blockIdx.y;
  int blk = blockIdx.x;                // 0..3 (128 positions)
  int wid = __builtin_amdgcn_readfirstlane(threadIdx.x >> 6);
  int lane = threadIdx.x & 63;
  int ln = lane & 15, kq = lane >> 4;
  int lh = wid & 1, ch = wid >> 1;     // wave-uniform
  int l0 = blk*128 + lh*64;            // l = l0 + lt*16 + ln
  int cbase = ch*64;                   // A-row c = cbase+ct*16+ln; D-row c = cbase+ct*16+kq*4+r
#define DECLB(ct) f32x4 bi##ct = *(const f32x4*)(b3 + cbase + ct*16 + kq*4);
  DECLB(0) DECLB(1) DECLB(2) DECLB(3)
#define DECLACC(lt,ct) f32x4 acc##lt##ct = bi##ct;
  TILES(DECLACC)
  const short* hB = h2t + ((size_t)b*LPAD + l0 + ln)*C2 + kq*8;  // + (lt*16 + t)*C2 + s*32
  const short* wA = w3b + (size_t)(cbase + ln)*C2 + kq*8;        // + (t*C3 + ct*16)*C2 + s*32
  #pragma unroll
  for (int t=0;t<3;t++){
    #pragma unroll
    for (int s=0;s<2;s++){
#define LDB(lt) short8 bv##lt = *(const short8*)(hB + (size_t)(lt*16 + t)*C2 + s*32);
      LDB(0) LDB(1) LDB(2) LDB(3)
#define LDA(ct) short8 av##ct = *(const short8*)(wA + (size_t)(t*C3 + ct*16)*C2 + s*32);
      LDA(0) LDA(1) LDA(2) LDA(3)
#define MM(lt,ct) acc##lt##ct = __builtin_amdgcn_mfma_f32_16x16x32_bf16(av##ct, bv##lt, acc##lt##ct, 0, 0, 0);
      TILES(MM)
#undef LDB
#undef LDA
    }
  }
  // stores: y3t[b][c][l], contiguous in ln per (kq,r) row
#define ST(lt,ct) { int l_ = l0 + lt*16 + ln; if (l_ < LEN3){ \
    float* yp_ = y3t + ((size_t)b*C3 + cbase + ct*16 + kq*4)*LEN3 + l_; \
    yp_[0]        = acc##lt##ct[0]; yp_[LEN3]     = acc##lt##ct[1]; \
    yp_[2*LEN3]   = acc##lt##ct[2]; yp_[3*LEN3]   = acc##lt##ct[3]; } }
  TILES(ST)
  // fused stats: per (ct,r) sum over this wave's 64 l values
  int pidx = b*8 + blk*2 + lh;
  #pragma unroll
  for (int ct=0;ct<4;ct++){
    float s0=0.f,s1=0.f,s2=0.f,s3=0.f,q0=0.f,q1=0.f,q2=0.f,q3=0.f;
#define ACCST(lt,CT) if (CT == ct){ int l_ = l0 + lt*16 + ln; if (l_ < LEN3){ \
      s0 += acc##lt##CT[0]; q0 = fmaf(acc##lt##CT[0], acc##lt##CT[0], q0); \
      s1 += acc##lt##CT[1]; q1 = fmaf(acc##lt##CT[1], acc##lt##CT[1], q1); \
      s2 += acc##lt##CT[2]; q2 = fmaf(acc##lt##CT[2], acc##lt##CT[2], q2); \
      s3 += acc##lt##CT[3]; q3 = fmaf(acc##lt##CT[3], acc##lt##CT[3], q3); } }
    TILES(ACCST)
#undef ACCST
    RED4L(s0) RED4L(s1) RED4L(s2) RED4L(s3)
    RED4L(q0) RED4L(q1) RED4L(q2) RED4L(q3)
    if (ln == 0){
      int c0 = cbase + ct*16 + kq*4;
      ps[(size_t)(c0+0)*NPART + pidx] = s0;  pq[(size_t)(c0+0)*NPART + pidx] = q0;
      ps[(size_t)(c0+1)*NPART + pidx] = s1;  pq[(size_t)(c0+1)*NPART + pidx] = q1;
      ps[(size_t)(c0+2)*NPART + pidx] = s2;  pq[(size_t)(c0+2)*NPART + pidx] = q2;
      ps[(size_t)(c0+3)*NPART + pidx] = s3;  pq[(size_t)(c0+3)*NPART + pidx] = q3;
    }
  }
}

// ---------------- K9: bn3+relu+mean over y3t [b][c][l] (contiguous rows) ----------------
__global__ __launch_bounds__(256) void k_out(float* __restrict__ out, const float* __restrict__ ws){
  const float* y3t = ws + OFF_Y3T;
  const float* st = ws + OFF_S3;
  int w = blockIdx.x*4 + (threadIdx.x>>6);
  int lane = threadIdx.x & 63;
  int b = w >> 7, c = w & 127;
  const float* p = y3t + ((size_t)b*C3 + c)*LEN3;
  float a = st[c], sh = st[C3+c];
  float s = 0.f;
  for (int i=lane; i<LEN3; i+=64) s += fmaxf(fmaf(a, p[i], sh), 0.f);
  RED6(s)
  if (lane==0) out[b*C3+c] = s * (1.0f/511.0f);
}

extern "C" void kernel_launch(void* const* d_in, const int* in_sizes, int n_in,
                              void* d_out, int out_size, void* d_ws, size_t ws_size,
                              hipStream_t stream) {
  const float* x   = (const float*)d_in[0];
  const float* c1w = (const float*)d_in[1];
  const float* c1b = (const float*)d_in[2];
  const float* w1  = (const float*)d_in[3];
  const float* b1  = (const float*)d_in[4];
  const float* g1  = (const float*)d_in[5];
  const float* be1 = (const float*)d_in[6];
  const float* w2  = (const float*)d_in[7];
  const float* b2  = (const float*)d_in[8];
  const float* g2  = (const float*)d_in[9];
  const float* be2 = (const float*)d_in[10];
  const float* w3  = (const float*)d_in[11];
  const float* b3  = (const float*)d_in[12];
  const float* g3  = (const float*)d_in[13];
  const float* be3 = (const float*)d_in[14];
  float* ws  = (float*)d_ws;
  float* out = (float*)d_out;

  hipLaunchKernelGGL(k_patch,  dim3(32,NB), dim3(256), 0, stream, x, c1b, ws);
  hipLaunchKernelGGL(k_wB,     dim3(KPAD/256, NP), dim3(256), 0, stream, c1w, ws);
  hipLaunchKernelGGL(k_wt,     dim3((3*C3*C2+255)/256), dim3(256), 0, stream, w2, w3, ws);
  hipLaunchKernelGGL(k_gemm,   dim3(64,4,4), dim3(256), 0, stream, ws);
  hipLaunchKernelGGL(k_conv1,  dim3(8,NB), dim3(256), 0, stream, w1, b1, ws);
  hipLaunchKernelGGL(k_stats,  dim3(NB,C1), dim3(256), 0, stream, ws+OFF_Y1, ws+OFF_PS, ws+OFF_PQ, C1, LEN1, NB);
  hipLaunchKernelGGL(k_fin,    dim3(C1), dim3(256), 0, stream, ws+OFF_PS, ws+OFF_PQ, g1, be1, ws+OFF_S1, C1, NB, 1.0/((double)NB*LEN1));
  hipLaunchKernelGGL(k_pool1,  dim3(4,C1,NB), dim3(256), 0, stream, ws);
  hipLaunchKernelGGL(k_conv2,  dim3(8,NB), dim3(256), 0, stream, b2, ws);
  hipLaunchKernelGGL(k_fin,    dim3(C2), dim3(256), 0, stream, ws+OFF_PS, ws+OFF_PQ, g2, be2, ws+OFF_S2, C2, NPART, 1.0/((double)NB*LEN2));
  hipLaunchKernelGGL(k_p2bf,   dim3((LEN3*C2+3*C2+255)/256, NB), dim3(256), 0, stream, ws);
  hipLaunchKernelGGL(k_conv3m, dim3(4,NB), dim3(256), 0, stream, b3, ws);
  hipLaunchKernelGGL(k_fin,    dim3(C3), dim3(256), 0, stream, ws+OFF_PS, ws+OFF_PQ, g3, be3, ws+OFF_S3, C3, NPART, 1.0/((double)NB*LEN3));
  hipLaunchKernelGGL(k_out,    dim3((NB*C3)/4), dim3(256), 0, stream, out, ws);
}